// Round 9
// baseline (2624.039 us; speedup 1.0000x reference)
//
#include <hip/hip_runtime.h>

// InverseFoldingModel: 3-layer message-passing GNN, MFMA bf16 hi/lo (2-term).
// R9: LDS-alias rework of fused kernel: P and O live in A's edge half,
// hsum/mv/rs in A pad rows 30/31 -> LDS 32768 B -> 5 blocks/CU.

#define NN   20000
#define KNN  30
#define H    128
#define EIN  240
#define NL   3
#define AOUT 20
#define CIN  384   // 2H + E
#define EPSV 1e-5f

typedef unsigned short u16;
typedef unsigned int   u32;
typedef float f32x16 __attribute__((ext_vector_type(16)));
typedef short s16x8  __attribute__((ext_vector_type(8)));
typedef short s16x4  __attribute__((ext_vector_type(4)));

#define MFMA32(acc, a, b) \
  asm("v_mfma_f32_32x32x16_bf16 %0, %1, %2, %0" : "+v"(acc) : "v"(a), "v"(b))

__device__ __forceinline__ u16 bh(float x) {           // f32 -> bf16 (RNE)
  u32 u = __float_as_uint(x);
  u += 0x7fffu + ((u >> 16) & 1u);
  return (u16)(u >> 16);
}
__device__ __forceinline__ float hf(u16 h) { return __uint_as_float(((u32)h) << 16); }
// packed 2x f32 -> 2x bf16 (lo16 = a, hi16 = b)
__device__ __forceinline__ u32 pk2(float a, float b) {
  u32 r; asm("v_cvt_pk_bf16_f32 %0, %1, %2" : "=v"(r) : "v"(a), "v"(b)); return r;
}

// packed-row layout: 128 elems -> 8 chunks x (16 hi u16 + 16 lo u16) = 256 u16
__device__ __forceinline__ int pko(int col) { return ((col >> 4) << 5) + (col & 15); }

// XOR-swizzled LDS index (u16 units); swizzle: byte ^= (row&7)<<4
__device__ __forceinline__ int axi(int row, int off) { return (row * 512 + off) ^ ((row & 7) << 3); }

// write 4 consecutive logical-k elements as hi4+lo4 (f32 source; edge_init only)
__device__ __forceinline__ void wrA4(u16* A, int row, int off, float4 v) {
  u16 h0 = bh(v.x), h1 = bh(v.y), h2 = bh(v.z), h3 = bh(v.w);
  s16x4 hv = { (short)h0, (short)h1, (short)h2, (short)h3 };
  s16x4 lv = { (short)bh(v.x - hf(h0)), (short)bh(v.y - hf(h1)),
               (short)bh(v.z - hf(h2)), (short)bh(v.w - hf(h3)) };
  *(s16x4*)(A + axi(row, off))      = hv;
  *(s16x4*)(A + axi(row, off + 16)) = lv;
}

// ---------------- weight repack ----------------
// pk layout: [coltile c<4][chunk s<nS][h<2][lane<64][8 u16]
__global__ __launch_bounds__(256) void repack_w(
    const float* __restrict__ W, u16* __restrict__ pk, int nS)
{
  int s = blockIdx.x;
  int t = threadIdx.x;
  int c = t >> 6, l = t & 63;
  int col = c * 32 + (l & 31);
  int kb  = s * 16 + (l >> 5) * 8;
  size_t base = ((size_t)(c * nS + s) * 2) * 512 + l * 8;
  #pragma unroll
  for (int i = 0; i < 8; ++i) {
    float v = W[(size_t)(kb + i) * H + col];
    u16 hi = bh(v);
    pk[base + i]       = hi;
    pk[base + 512 + i] = bh(v - hf(hi));
  }
}

// ---------------- init ----------------

__global__ __launch_bounds__(256) void node_init_kernel(
    const float* __restrict__ nf, const float* __restrict__ Wn,
    const float* __restrict__ bn, float* __restrict__ nodes,
    u16* __restrict__ nodes_pk)
{
  int tid = blockIdx.x * 256 + threadIdx.x;
  if (tid >= NN * H) return;
  int n = tid >> 7, h = tid & (H - 1);
  float acc = bn[h];
  #pragma unroll
  for (int i = 0; i < 6; ++i)
    acc = fmaf(nf[n * 6 + i], Wn[i * H + h], acc);
  nodes[tid] = acc;
  u16 hi = bh(acc);
  nodes_pk[(size_t)n * 256 + pko(h)]      = hi;
  nodes_pk[(size_t)n * 256 + pko(h) + 16] = bh(acc - hf(hi));
}

// edges = ef @ We + be (K=240 -> 15 chunks), packed hi/lo output
__global__ __launch_bounds__(256) void edge_init_mfma(
    const float* __restrict__ ef, const u16* __restrict__ pkWe,
    const float* __restrict__ be, u16* __restrict__ edges_pk)
{
  __shared__ __align__(16) u16 A[32 * 512];
  int r0 = blockIdx.x * 32, t = threadIdx.x;
  for (int u = t; u < 1920; u += 256) {
    int r = u & 31, c = u >> 5;                   // c 0..59
    int k = c * 4;
    float4 v = *(const float4*)(ef + (size_t)(r0 + r) * EIN + k);
    wrA4(A, r, (k >> 4) * 32 + (k & 15), v);
  }
  __syncthreads();
  int w = t >> 6, l = t & 63;
  int lane31 = l & 31, half = l >> 5;
  float bev = be[w * 32 + lane31];
  f32x16 acc;
  #pragma unroll
  for (int r = 0; r < 16; ++r) acc[r] = bev;
  #pragma unroll
  for (int s = 0; s < 15; ++s) {
    s16x8 ah = *(const s16x8*)(A + axi(lane31, s * 32 + half * 8));
    s16x8 al = *(const s16x8*)(A + axi(lane31, s * 32 + 16 + half * 8));
    const u16* pb = pkWe + (size_t)((w * 15 + s) * 2) * 512 + l * 8;
    s16x8 bhv = *(const s16x8*)(pb);
    MFMA32(acc, ah, bhv);
    MFMA32(acc, al, bhv);
  }
  int col = w * 32 + lane31;
  #pragma unroll
  for (int r = 0; r < 16; ++r) {
    int row = (r & 3) + 8 * (r >> 2) + 4 * half;
    float v = acc[r];
    u16 hi = bh(v);
    size_t base = (size_t)(r0 + row) * 256 + pko(col);
    edges_pk[base]      = hi;
    edges_pk[base + 16] = bh(v - hf(hi));
  }
}

// ---------------- shared pieces ----------------

// copy-staging: A rows 0..29 = [nbr_pk row | edge_pk row]; rows 30,31 untouched
// (pad rows: their MFMA output rows are masked everywhere).
__device__ __forceinline__ void stage_copy(
    const u16* __restrict__ nodes_pk, const u16* __restrict__ edges_pk,
    const int* __restrict__ knn, int n, int t, u16* A)
{
  int w = t >> 6, l = t & 63;
  int sub = l >> 5;
  int off = (l & 31) * 8;
  #pragma unroll
  for (int j = 0; j < 8; ++j) {
    int task = w * 16 + j * 2 + sub;
    int row  = task & 31;
    int part = task >> 5;           // 0 = nbr, 1 = edge
    if (row < KNN) {
      const u16* src = (part == 0)
        ? nodes_pk + (size_t)knn[n * KNN + row] * 256 + off
        : edges_pk + ((size_t)n * KNN + row) * 256 + off;
      s16x8 v = *(const s16x8*)src;
      *(s16x8*)(A + ((row * 512 + part * 256 + off) ^ ((row & 7) << 3))) = v;
    }
  }
}

// MLP1: acc = sp (broadcast over rows) + A @ W1bc, K=256; 2-term (a_hi+a_lo)xW_hi
__device__ __forceinline__ f32x16 mlp1_mfma(
    const u16* A, const u16* __restrict__ pk, float spv, int l)
{
  int lane31 = l & 31, half = l >> 5;
  f32x16 acc;
  #pragma unroll
  for (int r = 0; r < 16; ++r) acc[r] = spv;
  #pragma unroll
  for (int s = 0; s < 16; ++s) {
    s16x8 ah = *(const s16x8*)(A + axi(lane31, s * 32 + half * 8));
    s16x8 al = *(const s16x8*)(A + axi(lane31, s * 32 + 16 + half * 8));
    const u16* pb = pk + (size_t)(s * 2) * 512 + l * 8;
    s16x8 bhv = *(const s16x8*)(pb);
    MFMA32(acc, ah, bhv);
    MFMA32(acc, al, bhv);
  }
  return acc;
}

// sp = nodes @ W[0:128] + b  (only for layer-0 message path)
__global__ __launch_bounds__(256) void sp_kernel(
    const float* __restrict__ nodes, const float* __restrict__ W,
    const float* __restrict__ b, float* __restrict__ sp)
{
  __shared__ __align__(16) float xl[2][H];
  int n0 = blockIdx.x * 2, t = threadIdx.x;
  int row = t >> 7, col = t & (H - 1);
  xl[row][col] = nodes[(size_t)(n0 + row) * H + col];
  __syncthreads();
  float acc = b[col];
  for (int k = 0; k < H; k += 4) {
    float4 xv = *(const float4*)(&xl[row][k]);
    acc = fmaf(xv.x, W[(k + 0) * H + col], acc);
    acc = fmaf(xv.y, W[(k + 1) * H + col], acc);
    acc = fmaf(xv.z, W[(k + 2) * H + col], acc);
    acc = fmaf(xv.w, W[(k + 3) * H + col], acc);
  }
  sp[(size_t)(n0 + row) * H + col] = acc;
}

// ---------------- per-layer kernels ----------------

__global__ __launch_bounds__(256, 5) void msg_agg_mfma(
    const u16* __restrict__ nodes_pk, const u16* __restrict__ edges_pk,
    const int* __restrict__ knn, const float* __restrict__ sp,
    const u16* __restrict__ pkW1, const float* __restrict__ W2,
    const float* __restrict__ b2, float* __restrict__ agg)
{
  __shared__ __align__(16) u16 A[32 * 512];     // rows 30,31 = pad; hsum aliases row 30
  float* hsum = (float*)(A + 30 * 512);         // 128 f32
  int n = blockIdx.x, t = threadIdx.x;
  stage_copy(nodes_pk, edges_pk, knn, n, t, A);
  int w = t >> 6, l = t & 63;
  int lane31 = l & 31, half = l >> 5;
  float spv = sp[(size_t)n * H + w * 32 + lane31];
  __syncthreads();
  f32x16 acc = mlp1_mfma(A, pkW1 + (size_t)(w * 16) * 1024, spv, l);
  float ss = 0.f;
  #pragma unroll
  for (int r = 0; r < 16; ++r) {
    float v = fmaxf(acc[r], 0.f);
    if (r >= 14) v = half ? 0.f : v;           // mask pad rows 30,31
    ss += v;
  }
  ss += __shfl_xor(ss, 32);
  if (l < 32) hsum[w * 32 + l] = ss;           // benign race vs pad-row MFMA reads
  __syncthreads();
  if (t < H) {
    float a2 = 0.f;
    for (int k = 0; k < H; k += 4) {
      float4 hv = *(const float4*)(hsum + k);
      a2 = fmaf(hv.x, W2[(k + 0) * H + t], a2);
      a2 = fmaf(hv.y, W2[(k + 1) * H + t], a2);
      a2 = fmaf(hv.z, W2[(k + 2) * H + t], a2);
      a2 = fmaf(hv.w, W2[(k + 3) * H + t], a2);
    }
    agg[(size_t)n * H + t] = a2 + (float)KNN * b2[t];
  }
}

// node update + LN + fold both sp matvecs
__global__ __launch_bounds__(128) void node_upd2_kernel(
    float* __restrict__ nodes, const float* __restrict__ agg,
    const float* __restrict__ W1, const float* __restrict__ b1,
    const float* __restrict__ W2, const float* __restrict__ b2,
    const float* __restrict__ g, const float* __restrict__ bb,
    u16* __restrict__ nodes_pk,
    const float* __restrict__ eW1s, const float* __restrict__ eb1,
    float* __restrict__ sp_e,
    const float* __restrict__ mW1s, const float* __restrict__ mb1,
    float* __restrict__ sp_m)
{
  __shared__ __align__(16) float x[2 * H];
  __shared__ __align__(16) float h[H];
  __shared__ float red[2][2];
  int n = blockIdx.x, t = threadIdx.x;
  x[t] = nodes[(size_t)n * H + t];
  x[H + t] = agg[(size_t)n * H + t];
  __syncthreads();
  float acc = 0.f;
  for (int i = 0; i < 2 * H; i += 4) {
    float4 xv = *(const float4*)(x + i);
    acc = fmaf(xv.x, W1[(i + 0) * H + t], acc);
    acc = fmaf(xv.y, W1[(i + 1) * H + t], acc);
    acc = fmaf(xv.z, W1[(i + 2) * H + t], acc);
    acc = fmaf(xv.w, W1[(i + 3) * H + t], acc);
  }
  h[t] = fmaxf(acc + b1[t], 0.f);
  __syncthreads();
  float acc2 = 0.f;
  for (int j = 0; j < H; j += 4) {
    float4 hv = *(const float4*)(h + j);
    acc2 = fmaf(hv.x, W2[(j + 0) * H + t], acc2);
    acc2 = fmaf(hv.y, W2[(j + 1) * H + t], acc2);
    acc2 = fmaf(hv.z, W2[(j + 2) * H + t], acc2);
    acc2 = fmaf(hv.w, W2[(j + 3) * H + t], acc2);
  }
  float y = x[t] + acc2 + b2[t];
  float sum = y, sq = y * y;
  #pragma unroll
  for (int off = 1; off < 64; off <<= 1) {
    sum += __shfl_xor(sum, off);
    sq  += __shfl_xor(sq, off);
  }
  int wv = t >> 6;
  if ((t & 63) == 0) { red[wv][0] = sum; red[wv][1] = sq; }
  __syncthreads();
  float tot = red[0][0] + red[1][0];
  float tsq = red[0][1] + red[1][1];
  float mean = tot * (1.f / (float)H);
  float var  = tsq * (1.f / (float)H) - mean * mean;
  float o = (y - mean) * rsqrtf(var + EPSV) * g[t] + bb[t];
  nodes[(size_t)n * H + t] = o;
  u16 hi = bh(o);
  nodes_pk[(size_t)n * 256 + pko(t)]      = hi;
  nodes_pk[(size_t)n * 256 + pko(t) + 16] = bh(o - hf(hi));
  __syncthreads();
  x[t] = o;
  __syncthreads();
  float ae = eb1[t], am = mb1[t];
  for (int k = 0; k < H; k += 4) {
    float4 xv = *(const float4*)(x + k);
    ae = fmaf(xv.x, eW1s[(k + 0) * H + t], ae);
    ae = fmaf(xv.y, eW1s[(k + 1) * H + t], ae);
    ae = fmaf(xv.z, eW1s[(k + 2) * H + t], ae);
    ae = fmaf(xv.w, eW1s[(k + 3) * H + t], ae);
    am = fmaf(xv.x, mW1s[(k + 0) * H + t], am);
    am = fmaf(xv.y, mW1s[(k + 1) * H + t], am);
    am = fmaf(xv.z, mW1s[(k + 2) * H + t], am);
    am = fmaf(xv.w, mW1s[(k + 3) * H + t], am);
  }
  sp_e[(size_t)n * H + t] = ae;
  sp_m[(size_t)n * H + t] = am;
}

// fused: edge_upd(l) + msg_agg(l+1). All scratch lives inside A (32 KB total):
// P and O alias A's edge half; hsum/mv/rs alias pad rows 30,31.
__global__ __launch_bounds__(256, 5) void fused_edge_msg(
    const u16* __restrict__ nodes_pk, u16* __restrict__ edges_pk,
    const int* __restrict__ knn,
    const float* __restrict__ sp_e, const float* __restrict__ sp_m,
    const u16* __restrict__ pkEW1, const u16* __restrict__ pkEW2,
    const float* __restrict__ eb2, const float* __restrict__ ge,
    const float* __restrict__ gbb,
    const u16* __restrict__ pkMW1, const float* __restrict__ mW2,
    const float* __restrict__ mb2, float* __restrict__ agg,
    int writeEdges)
{
  __shared__ __align__(16) u16 A[32 * 512];     // 32 KB total
  float* hsum = (float*)(A + 30 * 512);         // 128 f32 (row 30, nbr half)
  float* mv   = (float*)(A + 31 * 512);         // 32 f32 (row 31, nbr half)
  float* rs   = mv + 32;                        // 32 f32
  float* Af   = (float*)A;

  int n = blockIdx.x, t = threadIdx.x;
  stage_copy(nodes_pk, edges_pk, knn, n, t, A);
  int w = t >> 6, l = t & 63;
  int lane31 = l & 31, half = l >> 5;
  int col = w * 32 + lane31;
  float spe = sp_e[(size_t)n * H + col];
  float spm = sp_m[(size_t)n * H + col];
  int coff = 256 + pko(col);
  __syncthreads();                              // 1: A staged
  f32x16 acc = mlp1_mfma(A, pkEW1 + (size_t)(w * 16) * 1024, spe, l);
  // residual from A edge half (old edges)
  float res[16];
  #pragma unroll
  for (int r = 0; r < 16; ++r) {
    int row = (r & 3) + 8 * (r >> 2) + 4 * half;
    res[r] = (row < KNN)
      ? hf(A[axi(row, coff)]) + hf(A[axi(row, coff + 16)]) : 0.f;
  }
  __syncthreads();                              // 2: all A-edge reads done
  // P = relu(acc) hi/lo into A edge half (same pko slots as old edges)
  #pragma unroll
  for (int r = 0; r < 16; r += 2) {
    int row0 = (r & 3) + 8 * (r >> 2) + 4 * half;
    if (row0 < KNN) {
      float v0 = fmaxf(acc[r], 0.f), v1 = fmaxf(acc[r + 1], 0.f);
      u32 hp = pk2(v0, v1);
      float l0 = v0 - __uint_as_float(hp << 16);
      float l1 = v1 - __uint_as_float(hp & 0xffff0000u);
      u32 lp = pk2(l0, l1);
      A[axi(row0, coff)]          = (u16)hp;
      A[axi(row0, coff + 16)]     = (u16)lp;
      A[axi(row0 + 1, coff)]      = (u16)(hp >> 16);
      A[axi(row0 + 1, coff + 16)] = (u16)(lp >> 16);
    }
  }
  __syncthreads();                              // 3: P ready
  // MLP2: a2 = P @ eW2 + eb2 (2-term); P rows 30,31 garbage -> masked rows only
  float b2v = eb2[col];
  f32x16 a2;
  #pragma unroll
  for (int r = 0; r < 16; ++r) a2[r] = b2v;
  #pragma unroll
  for (int s = 0; s < 8; ++s) {
    s16x8 ah = *(const s16x8*)(A + axi(lane31, 256 + s * 32 + half * 8));
    s16x8 al = *(const s16x8*)(A + axi(lane31, 256 + s * 32 + 16 + half * 8));
    const u16* pb = pkEW2 + (size_t)((w * 8 + s) * 2) * 512 + l * 8;
    s16x8 bhv = *(const s16x8*)(pb);
    MFMA32(a2, ah, bhv);
    MFMA32(a2, al, bhv);
  }
  float y[16];
  #pragma unroll
  for (int r = 0; r < 16; ++r) y[r] = a2[r] + res[r];
  __syncthreads();                              // 4: all P reads done
  // O = y into A edge half as f32, XOR swizzle c^((row&7)<<2)
  #pragma unroll
  for (int r = 0; r < 16; ++r) {
    int row = (r & 3) + 8 * (r >> 2) + 4 * half;
    if (row < KNN)
      Af[row * 256 + 128 + (col ^ ((row & 7) << 2))] = y[r];
  }
  __syncthreads();                              // 5: O ready
  // stats: 8 threads per row, 16 cols each, 3-level shfl
  {
    int srow = t >> 3, sub = t & 7;
    if (srow < KNN) {
      float s = 0.f, q = 0.f;
      #pragma unroll
      for (int qd = 0; qd < 4; ++qd) {
        int c0 = (sub * 16 + qd * 4) ^ ((srow & 7) << 2);
        float4 v = *(const float4*)(Af + srow * 256 + 128 + c0);
        s += v.x + v.y + v.z + v.w;
        q = fmaf(v.x, v.x, q); q = fmaf(v.y, v.y, q);
        q = fmaf(v.z, v.z, q); q = fmaf(v.w, v.w, q);
      }
      #pragma unroll
      for (int off = 1; off < 8; off <<= 1) {
        s += __shfl_xor(s, off);
        q += __shfl_xor(q, off);
      }
      if (sub == 0) {
        float mean = s * (1.f / (float)H);
        mv[srow] = mean;
        rs[srow] = rsqrtf(q * (1.f / (float)H) - mean * mean + EPSV);
      }
    }
  }
  __syncthreads();                              // 6: stats ready, O reads done
  // normalize; optional global store; write new edges into A edge half
  {
    float gv = ge[col], bbv = gbb[col];
    #pragma unroll
    for (int r = 0; r < 16; r += 2) {
      int row0 = (r & 3) + 8 * (r >> 2) + 4 * half;
      if (row0 < KNN) {
        float o0 = (y[r]     - mv[row0])     * rs[row0]     * gv + bbv;
        float o1 = (y[r + 1] - mv[row0 + 1]) * rs[row0 + 1] * gv + bbv;
        u32 hp = pk2(o0, o1);
        float l0 = o0 - __uint_as_float(hp << 16);
        float l1 = o1 - __uint_as_float(hp & 0xffff0000u);
        u32 lp = pk2(l0, l1);
        if (writeEdges) {
          size_t b0 = ((size_t)n * KNN + row0) * 256 + pko(col);
          edges_pk[b0]            = (u16)hp;
          edges_pk[b0 + 16]       = (u16)lp;
          edges_pk[b0 + 256]      = (u16)(hp >> 16);
          edges_pk[b0 + 256 + 16] = (u16)(lp >> 16);
        }
        A[axi(row0, coff)]          = (u16)hp;
        A[axi(row0, coff + 16)]     = (u16)lp;
        A[axi(row0 + 1, coff)]      = (u16)(hp >> 16);
        A[axi(row0 + 1, coff + 16)] = (u16)(lp >> 16);
      }
    }
  }
  __syncthreads();                              // 7: A = [nbr | new edges]
  // message MLP1 on updated A
  f32x16 macc = mlp1_mfma(A, pkMW1 + (size_t)(w * 16) * 1024, spm, l);
  float ss = 0.f;
  #pragma unroll
  for (int r = 0; r < 16; ++r) {
    float v = fmaxf(macc[r], 0.f);
    if (r >= 14) v = half ? 0.f : v;
    ss += v;
  }
  ss += __shfl_xor(ss, 32);
  if (l < 32) hsum[w * 32 + l] = ss;
  __syncthreads();                              // 8: hsum ready
  if (t < H) {
    float a2m = 0.f;
    for (int k = 0; k < H; k += 4) {
      float4 hv = *(const float4*)(hsum + k);
      a2m = fmaf(hv.x, mW2[(k + 0) * H + t], a2m);
      a2m = fmaf(hv.y, mW2[(k + 1) * H + t], a2m);
      a2m = fmaf(hv.z, mW2[(k + 2) * H + t], a2m);
      a2m = fmaf(hv.w, mW2[(k + 3) * H + t], a2m);
    }
    agg[(size_t)n * H + t] = a2m + (float)KNN * mb2[t];
  }
}

// ---------------- output ----------------

__global__ __launch_bounds__(64) void out_kernel(
    const float* __restrict__ nodes, const float* __restrict__ Wout,
    const float* __restrict__ bout, float* __restrict__ out)
{
  __shared__ float x[H];
  int n = blockIdx.x, t = threadIdx.x;
  x[t] = nodes[(size_t)n * H + t];
  x[64 + t] = nodes[(size_t)n * H + 64 + t];
  __syncthreads();
  if (t < AOUT) {
    float acc = bout[t];
    for (int hh = 0; hh < H; ++hh)
      acc = fmaf(x[hh], Wout[hh * AOUT + t], acc);
    out[n * AOUT + t] = acc;
  }
}

// ---------------- launch ----------------

extern "C" void kernel_launch(void* const* d_in, const int* in_sizes, int n_in,
                              void* d_out, int out_size, void* d_ws, size_t ws_size,
                              hipStream_t stream) {
  const float* nf    = (const float*)d_in[0];
  const float* ef    = (const float*)d_in[1];
  const int*   knn   = (const int*)  d_in[2];
  const float* Wn    = (const float*)d_in[3];
  const float* bn    = (const float*)d_in[4];
  const float* We    = (const float*)d_in[5];
  const float* be    = (const float*)d_in[6];
  const float* mW1   = (const float*)d_in[7];
  const float* mb1   = (const float*)d_in[8];
  const float* mW2   = (const float*)d_in[9];
  const float* mb2   = (const float*)d_in[10];
  const float* nW1   = (const float*)d_in[11];
  const float* nb1   = (const float*)d_in[12];
  const float* nW2   = (const float*)d_in[13];
  const float* nb2   = (const float*)d_in[14];
  const float* eW1   = (const float*)d_in[15];
  const float* eb1   = (const float*)d_in[16];
  const float* eW2   = (const float*)d_in[17];
  const float* eb2   = (const float*)d_in[18];
  const float* gn    = (const float*)d_in[19];
  const float* bnrm  = (const float*)d_in[20];
  const float* ge    = (const float*)d_in[21];
  const float* benrm = (const float*)d_in[22];
  const float* Wout  = (const float*)d_in[23];
  const float* bout  = (const float*)d_in[24];
  float* out = (float*)d_out;

  float* ws     = (float*)d_ws;
  float* nodes  = ws;                                  // N*H f32
  float* aggse  = ws + (size_t)NN * H;                 // N*H f32: agg, aliased by sp_e
  float* sp_m   = ws + (size_t)2 * NN * H;             // N*H f32
  u16* nodes_pk = (u16*)(ws + (size_t)3 * NN * H);     // N*256 u16
  u16* edges_pk = nodes_pk + (size_t)NN * 256;         // N*K*256 u16 (307 MB)
  u16* pk       = edges_pk + (size_t)NN * KNN * 256;   // packed weights
  u16* pkWe = pk;                       // 4*15*2*512 = 61440
  u16* pkM1 = pkWe + 61440;             // 3 x 65536
  u16* pkE1 = pkM1 + 3 * 65536;         // 3 x 65536
  u16* pkE2 = pkE1 + 3 * 65536;         // 3 x 32768
  float* sp_e = aggse;                  // alias: per-block read(sp_e)->write(agg) is safe

  node_init_kernel<<<(NN * H + 255) / 256, 256, 0, stream>>>(nf, Wn, bn, nodes, nodes_pk);
  repack_w<<<15, 256, 0, stream>>>(We, pkWe, 15);
  for (int l = 0; l < NL; ++l) {
    repack_w<<<16, 256, 0, stream>>>(mW1 + (size_t)l * CIN * H + 128 * H, pkM1 + l * 65536, 16);
    repack_w<<<16, 256, 0, stream>>>(eW1 + (size_t)l * CIN * H + 128 * H, pkE1 + l * 65536, 16);
    repack_w<<<8,  256, 0, stream>>>(eW2 + (size_t)l * H * H,             pkE2 + l * 32768, 8);
  }
  edge_init_mfma<<<NN * KNN / 32, 256, 0, stream>>>(ef, pkWe, be, edges_pk);

  // layer-0 message pass (standalone)
  sp_kernel<<<NN / 2, 256, 0, stream>>>(nodes, mW1, mb1, sp_m);
  msg_agg_mfma<<<NN, 256, 0, stream>>>(nodes_pk, edges_pk, knn, sp_m,
      pkM1, mW2, mb2, aggse);

  for (int l = 0; l < NL; ++l) {
    const float* mW1n = (l < 2) ? mW1 + (size_t)(l + 1) * CIN * H : mW1;
    const float* mb1n = (l < 2) ? mb1 + (size_t)(l + 1) * H       : mb1;
    node_upd2_kernel<<<NN, 128, 0, stream>>>(nodes, aggse,
        nW1 + (size_t)l * 2 * H * H, nb1 + l * H,
        nW2 + (size_t)l * H * H, nb2 + l * H,
        gn + l * H, bnrm + l * H, nodes_pk,
        eW1 + (size_t)l * CIN * H, eb1 + l * H, sp_e,
        mW1n, mb1n, sp_m);
    if (l < 2) {
      fused_edge_msg<<<NN, 256, 0, stream>>>(nodes_pk, edges_pk, knn,
          sp_e, sp_m,
          pkE1 + l * 65536, pkE2 + l * 32768, eb2 + l * H,
          ge + l * H, benrm + l * H,
          pkM1 + (l + 1) * 65536, mW2 + (size_t)(l + 1) * H * H,
          mb2 + (l + 1) * H, aggse, (l == 0) ? 1 : 0);
    }
  }
  out_kernel<<<NN, 64, 0, stream>>>(nodes, Wout, bout, out);
}

// Round 10
// 2069.307 us; speedup vs baseline: 1.2681x; 1.2681x over previous
//
#include <hip/hip_runtime.h>

// InverseFoldingModel: 3-layer message-passing GNN, MFMA bf16 hi/lo (2-term).
// R10 = R9 LDS-alias layout (32 KB fused kernel) with plain launch bounds:
// the (256,5) hint capped VGPR at 48 and spilled ~1 GB to scratch (R9 regression).

#define NN   20000
#define KNN  30
#define H    128
#define EIN  240
#define NL   3
#define AOUT 20
#define CIN  384   // 2H + E
#define EPSV 1e-5f

typedef unsigned short u16;
typedef unsigned int   u32;
typedef float f32x16 __attribute__((ext_vector_type(16)));
typedef short s16x8  __attribute__((ext_vector_type(8)));
typedef short s16x4  __attribute__((ext_vector_type(4)));

#define MFMA32(acc, a, b) \
  asm("v_mfma_f32_32x32x16_bf16 %0, %1, %2, %0" : "+v"(acc) : "v"(a), "v"(b))

__device__ __forceinline__ u16 bh(float x) {           // f32 -> bf16 (RNE)
  u32 u = __float_as_uint(x);
  u += 0x7fffu + ((u >> 16) & 1u);
  return (u16)(u >> 16);
}
__device__ __forceinline__ float hf(u16 h) { return __uint_as_float(((u32)h) << 16); }
// packed 2x f32 -> 2x bf16 (lo16 = a, hi16 = b)
__device__ __forceinline__ u32 pk2(float a, float b) {
  u32 r; asm("v_cvt_pk_bf16_f32 %0, %1, %2" : "=v"(r) : "v"(a), "v"(b)); return r;
}

// packed-row layout: 128 elems -> 8 chunks x (16 hi u16 + 16 lo u16) = 256 u16
__device__ __forceinline__ int pko(int col) { return ((col >> 4) << 5) + (col & 15); }

// XOR-swizzled LDS index (u16 units); swizzle: byte ^= (row&7)<<4
__device__ __forceinline__ int axi(int row, int off) { return (row * 512 + off) ^ ((row & 7) << 3); }

// write 4 consecutive logical-k elements as hi4+lo4 (f32 source; edge_init only)
__device__ __forceinline__ void wrA4(u16* A, int row, int off, float4 v) {
  u16 h0 = bh(v.x), h1 = bh(v.y), h2 = bh(v.z), h3 = bh(v.w);
  s16x4 hv = { (short)h0, (short)h1, (short)h2, (short)h3 };
  s16x4 lv = { (short)bh(v.x - hf(h0)), (short)bh(v.y - hf(h1)),
               (short)bh(v.z - hf(h2)), (short)bh(v.w - hf(h3)) };
  *(s16x4*)(A + axi(row, off))      = hv;
  *(s16x4*)(A + axi(row, off + 16)) = lv;
}

// ---------------- weight repack ----------------
// pk layout: [coltile c<4][chunk s<nS][h<2][lane<64][8 u16]
__global__ __launch_bounds__(256) void repack_w(
    const float* __restrict__ W, u16* __restrict__ pk, int nS)
{
  int s = blockIdx.x;
  int t = threadIdx.x;
  int c = t >> 6, l = t & 63;
  int col = c * 32 + (l & 31);
  int kb  = s * 16 + (l >> 5) * 8;
  size_t base = ((size_t)(c * nS + s) * 2) * 512 + l * 8;
  #pragma unroll
  for (int i = 0; i < 8; ++i) {
    float v = W[(size_t)(kb + i) * H + col];
    u16 hi = bh(v);
    pk[base + i]       = hi;
    pk[base + 512 + i] = bh(v - hf(hi));
  }
}

// ---------------- init ----------------

__global__ __launch_bounds__(256) void node_init_kernel(
    const float* __restrict__ nf, const float* __restrict__ Wn,
    const float* __restrict__ bn, float* __restrict__ nodes,
    u16* __restrict__ nodes_pk)
{
  int tid = blockIdx.x * 256 + threadIdx.x;
  if (tid >= NN * H) return;
  int n = tid >> 7, h = tid & (H - 1);
  float acc = bn[h];
  #pragma unroll
  for (int i = 0; i < 6; ++i)
    acc = fmaf(nf[n * 6 + i], Wn[i * H + h], acc);
  nodes[tid] = acc;
  u16 hi = bh(acc);
  nodes_pk[(size_t)n * 256 + pko(h)]      = hi;
  nodes_pk[(size_t)n * 256 + pko(h) + 16] = bh(acc - hf(hi));
}

// edges = ef @ We + be (K=240 -> 15 chunks), packed hi/lo output
__global__ __launch_bounds__(256) void edge_init_mfma(
    const float* __restrict__ ef, const u16* __restrict__ pkWe,
    const float* __restrict__ be, u16* __restrict__ edges_pk)
{
  __shared__ __align__(16) u16 A[32 * 512];
  int r0 = blockIdx.x * 32, t = threadIdx.x;
  for (int u = t; u < 1920; u += 256) {
    int r = u & 31, c = u >> 5;                   // c 0..59
    int k = c * 4;
    float4 v = *(const float4*)(ef + (size_t)(r0 + r) * EIN + k);
    wrA4(A, r, (k >> 4) * 32 + (k & 15), v);
  }
  __syncthreads();
  int w = t >> 6, l = t & 63;
  int lane31 = l & 31, half = l >> 5;
  float bev = be[w * 32 + lane31];
  f32x16 acc;
  #pragma unroll
  for (int r = 0; r < 16; ++r) acc[r] = bev;
  #pragma unroll
  for (int s = 0; s < 15; ++s) {
    s16x8 ah = *(const s16x8*)(A + axi(lane31, s * 32 + half * 8));
    s16x8 al = *(const s16x8*)(A + axi(lane31, s * 32 + 16 + half * 8));
    const u16* pb = pkWe + (size_t)((w * 15 + s) * 2) * 512 + l * 8;
    s16x8 bhv = *(const s16x8*)(pb);
    MFMA32(acc, ah, bhv);
    MFMA32(acc, al, bhv);
  }
  int col = w * 32 + lane31;
  #pragma unroll
  for (int r = 0; r < 16; ++r) {
    int row = (r & 3) + 8 * (r >> 2) + 4 * half;
    float v = acc[r];
    u16 hi = bh(v);
    size_t base = (size_t)(r0 + row) * 256 + pko(col);
    edges_pk[base]      = hi;
    edges_pk[base + 16] = bh(v - hf(hi));
  }
}

// ---------------- shared pieces ----------------

// copy-staging: A rows 0..29 = [nbr_pk row | edge_pk row]; rows 30,31 untouched
// (pad rows: their MFMA output rows are masked everywhere).
__device__ __forceinline__ void stage_copy(
    const u16* __restrict__ nodes_pk, const u16* __restrict__ edges_pk,
    const int* __restrict__ knn, int n, int t, u16* A)
{
  int w = t >> 6, l = t & 63;
  int sub = l >> 5;
  int off = (l & 31) * 8;
  #pragma unroll
  for (int j = 0; j < 8; ++j) {
    int task = w * 16 + j * 2 + sub;
    int row  = task & 31;
    int part = task >> 5;           // 0 = nbr, 1 = edge
    if (row < KNN) {
      const u16* src = (part == 0)
        ? nodes_pk + (size_t)knn[n * KNN + row] * 256 + off
        : edges_pk + ((size_t)n * KNN + row) * 256 + off;
      s16x8 v = *(const s16x8*)src;
      *(s16x8*)(A + ((row * 512 + part * 256 + off) ^ ((row & 7) << 3))) = v;
    }
  }
}

// MLP1: acc = sp (broadcast over rows) + A @ W1bc, K=256; 2-term (a_hi+a_lo)xW_hi
__device__ __forceinline__ f32x16 mlp1_mfma(
    const u16* A, const u16* __restrict__ pk, float spv, int l)
{
  int lane31 = l & 31, half = l >> 5;
  f32x16 acc;
  #pragma unroll
  for (int r = 0; r < 16; ++r) acc[r] = spv;
  #pragma unroll
  for (int s = 0; s < 16; ++s) {
    s16x8 ah = *(const s16x8*)(A + axi(lane31, s * 32 + half * 8));
    s16x8 al = *(const s16x8*)(A + axi(lane31, s * 32 + 16 + half * 8));
    const u16* pb = pk + (size_t)(s * 2) * 512 + l * 8;
    s16x8 bhv = *(const s16x8*)(pb);
    MFMA32(acc, ah, bhv);
    MFMA32(acc, al, bhv);
  }
  return acc;
}

// sp = nodes @ W[0:128] + b  (only for layer-0 message path)
__global__ __launch_bounds__(256) void sp_kernel(
    const float* __restrict__ nodes, const float* __restrict__ W,
    const float* __restrict__ b, float* __restrict__ sp)
{
  __shared__ __align__(16) float xl[2][H];
  int n0 = blockIdx.x * 2, t = threadIdx.x;
  int row = t >> 7, col = t & (H - 1);
  xl[row][col] = nodes[(size_t)(n0 + row) * H + col];
  __syncthreads();
  float acc = b[col];
  for (int k = 0; k < H; k += 4) {
    float4 xv = *(const float4*)(&xl[row][k]);
    acc = fmaf(xv.x, W[(k + 0) * H + col], acc);
    acc = fmaf(xv.y, W[(k + 1) * H + col], acc);
    acc = fmaf(xv.z, W[(k + 2) * H + col], acc);
    acc = fmaf(xv.w, W[(k + 3) * H + col], acc);
  }
  sp[(size_t)(n0 + row) * H + col] = acc;
}

// ---------------- per-layer kernels ----------------

__global__ __launch_bounds__(256) void msg_agg_mfma(
    const u16* __restrict__ nodes_pk, const u16* __restrict__ edges_pk,
    const int* __restrict__ knn, const float* __restrict__ sp,
    const u16* __restrict__ pkW1, const float* __restrict__ W2,
    const float* __restrict__ b2, float* __restrict__ agg)
{
  __shared__ __align__(16) u16 A[32 * 512];     // rows 30,31 = pad; hsum aliases row 30
  float* hsum = (float*)(A + 30 * 512);         // 128 f32
  int n = blockIdx.x, t = threadIdx.x;
  stage_copy(nodes_pk, edges_pk, knn, n, t, A);
  int w = t >> 6, l = t & 63;
  int lane31 = l & 31, half = l >> 5;
  float spv = sp[(size_t)n * H + w * 32 + lane31];
  __syncthreads();
  f32x16 acc = mlp1_mfma(A, pkW1 + (size_t)(w * 16) * 1024, spv, l);
  float ss = 0.f;
  #pragma unroll
  for (int r = 0; r < 16; ++r) {
    float v = fmaxf(acc[r], 0.f);
    if (r >= 14) v = half ? 0.f : v;           // mask pad rows 30,31
    ss += v;
  }
  ss += __shfl_xor(ss, 32);
  if (l < 32) hsum[w * 32 + l] = ss;           // benign race vs pad-row MFMA reads
  __syncthreads();
  if (t < H) {
    float a2 = 0.f;
    for (int k = 0; k < H; k += 4) {
      float4 hv = *(const float4*)(hsum + k);
      a2 = fmaf(hv.x, W2[(k + 0) * H + t], a2);
      a2 = fmaf(hv.y, W2[(k + 1) * H + t], a2);
      a2 = fmaf(hv.z, W2[(k + 2) * H + t], a2);
      a2 = fmaf(hv.w, W2[(k + 3) * H + t], a2);
    }
    agg[(size_t)n * H + t] = a2 + (float)KNN * b2[t];
  }
}

// node update + LN + fold both sp matvecs
__global__ __launch_bounds__(128) void node_upd2_kernel(
    float* __restrict__ nodes, const float* __restrict__ agg,
    const float* __restrict__ W1, const float* __restrict__ b1,
    const float* __restrict__ W2, const float* __restrict__ b2,
    const float* __restrict__ g, const float* __restrict__ bb,
    u16* __restrict__ nodes_pk,
    const float* __restrict__ eW1s, const float* __restrict__ eb1,
    float* __restrict__ sp_e,
    const float* __restrict__ mW1s, const float* __restrict__ mb1,
    float* __restrict__ sp_m)
{
  __shared__ __align__(16) float x[2 * H];
  __shared__ __align__(16) float h[H];
  __shared__ float red[2][2];
  int n = blockIdx.x, t = threadIdx.x;
  x[t] = nodes[(size_t)n * H + t];
  x[H + t] = agg[(size_t)n * H + t];
  __syncthreads();
  float acc = 0.f;
  for (int i = 0; i < 2 * H; i += 4) {
    float4 xv = *(const float4*)(x + i);
    acc = fmaf(xv.x, W1[(i + 0) * H + t], acc);
    acc = fmaf(xv.y, W1[(i + 1) * H + t], acc);
    acc = fmaf(xv.z, W1[(i + 2) * H + t], acc);
    acc = fmaf(xv.w, W1[(i + 3) * H + t], acc);
  }
  h[t] = fmaxf(acc + b1[t], 0.f);
  __syncthreads();
  float acc2 = 0.f;
  for (int j = 0; j < H; j += 4) {
    float4 hv = *(const float4*)(h + j);
    acc2 = fmaf(hv.x, W2[(j + 0) * H + t], acc2);
    acc2 = fmaf(hv.y, W2[(j + 1) * H + t], acc2);
    acc2 = fmaf(hv.z, W2[(j + 2) * H + t], acc2);
    acc2 = fmaf(hv.w, W2[(j + 3) * H + t], acc2);
  }
  float y = x[t] + acc2 + b2[t];
  float sum = y, sq = y * y;
  #pragma unroll
  for (int off = 1; off < 64; off <<= 1) {
    sum += __shfl_xor(sum, off);
    sq  += __shfl_xor(sq, off);
  }
  int wv = t >> 6;
  if ((t & 63) == 0) { red[wv][0] = sum; red[wv][1] = sq; }
  __syncthreads();
  float tot = red[0][0] + red[1][0];
  float tsq = red[0][1] + red[1][1];
  float mean = tot * (1.f / (float)H);
  float var  = tsq * (1.f / (float)H) - mean * mean;
  float o = (y - mean) * rsqrtf(var + EPSV) * g[t] + bb[t];
  nodes[(size_t)n * H + t] = o;
  u16 hi = bh(o);
  nodes_pk[(size_t)n * 256 + pko(t)]      = hi;
  nodes_pk[(size_t)n * 256 + pko(t) + 16] = bh(o - hf(hi));
  __syncthreads();
  x[t] = o;
  __syncthreads();
  float ae = eb1[t], am = mb1[t];
  for (int k = 0; k < H; k += 4) {
    float4 xv = *(const float4*)(x + k);
    ae = fmaf(xv.x, eW1s[(k + 0) * H + t], ae);
    ae = fmaf(xv.y, eW1s[(k + 1) * H + t], ae);
    ae = fmaf(xv.z, eW1s[(k + 2) * H + t], ae);
    ae = fmaf(xv.w, eW1s[(k + 3) * H + t], ae);
    am = fmaf(xv.x, mW1s[(k + 0) * H + t], am);
    am = fmaf(xv.y, mW1s[(k + 1) * H + t], am);
    am = fmaf(xv.z, mW1s[(k + 2) * H + t], am);
    am = fmaf(xv.w, mW1s[(k + 3) * H + t], am);
  }
  sp_e[(size_t)n * H + t] = ae;
  sp_m[(size_t)n * H + t] = am;
}

// fused: edge_upd(l) + msg_agg(l+1). All scratch lives inside A (32 KB total):
// P and O alias A's edge half; hsum/mv/rs alias pad rows 30,31.
__global__ __launch_bounds__(256) void fused_edge_msg(
    const u16* __restrict__ nodes_pk, u16* __restrict__ edges_pk,
    const int* __restrict__ knn,
    const float* __restrict__ sp_e, const float* __restrict__ sp_m,
    const u16* __restrict__ pkEW1, const u16* __restrict__ pkEW2,
    const float* __restrict__ eb2, const float* __restrict__ ge,
    const float* __restrict__ gbb,
    const u16* __restrict__ pkMW1, const float* __restrict__ mW2,
    const float* __restrict__ mb2, float* __restrict__ agg,
    int writeEdges)
{
  __shared__ __align__(16) u16 A[32 * 512];     // 32 KB total
  float* hsum = (float*)(A + 30 * 512);         // 128 f32 (row 30, nbr half)
  float* mv   = (float*)(A + 31 * 512);         // 32 f32 (row 31, nbr half)
  float* rs   = mv + 32;                        // 32 f32
  float* Af   = (float*)A;

  int n = blockIdx.x, t = threadIdx.x;
  stage_copy(nodes_pk, edges_pk, knn, n, t, A);
  int w = t >> 6, l = t & 63;
  int lane31 = l & 31, half = l >> 5;
  int col = w * 32 + lane31;
  float spe = sp_e[(size_t)n * H + col];
  float spm = sp_m[(size_t)n * H + col];
  int coff = 256 + pko(col);
  __syncthreads();                              // 1: A staged
  f32x16 acc = mlp1_mfma(A, pkEW1 + (size_t)(w * 16) * 1024, spe, l);
  // residual from A edge half (old edges)
  float res[16];
  #pragma unroll
  for (int r = 0; r < 16; ++r) {
    int row = (r & 3) + 8 * (r >> 2) + 4 * half;
    res[r] = (row < KNN)
      ? hf(A[axi(row, coff)]) + hf(A[axi(row, coff + 16)]) : 0.f;
  }
  __syncthreads();                              // 2: all A-edge reads done
  // P = relu(acc) hi/lo into A edge half (same pko slots as old edges)
  #pragma unroll
  for (int r = 0; r < 16; r += 2) {
    int row0 = (r & 3) + 8 * (r >> 2) + 4 * half;
    if (row0 < KNN) {
      float v0 = fmaxf(acc[r], 0.f), v1 = fmaxf(acc[r + 1], 0.f);
      u32 hp = pk2(v0, v1);
      float l0 = v0 - __uint_as_float(hp << 16);
      float l1 = v1 - __uint_as_float(hp & 0xffff0000u);
      u32 lp = pk2(l0, l1);
      A[axi(row0, coff)]          = (u16)hp;
      A[axi(row0, coff + 16)]     = (u16)lp;
      A[axi(row0 + 1, coff)]      = (u16)(hp >> 16);
      A[axi(row0 + 1, coff + 16)] = (u16)(lp >> 16);
    }
  }
  __syncthreads();                              // 3: P ready
  // MLP2: a2 = P @ eW2 + eb2 (2-term); P rows 30,31 garbage -> masked rows only
  float b2v = eb2[col];
  f32x16 a2;
  #pragma unroll
  for (int r = 0; r < 16; ++r) a2[r] = b2v;
  #pragma unroll
  for (int s = 0; s < 8; ++s) {
    s16x8 ah = *(const s16x8*)(A + axi(lane31, 256 + s * 32 + half * 8));
    s16x8 al = *(const s16x8*)(A + axi(lane31, 256 + s * 32 + 16 + half * 8));
    const u16* pb = pkEW2 + (size_t)((w * 8 + s) * 2) * 512 + l * 8;
    s16x8 bhv = *(const s16x8*)(pb);
    MFMA32(a2, ah, bhv);
    MFMA32(a2, al, bhv);
  }
  float y[16];
  #pragma unroll
  for (int r = 0; r < 16; ++r) y[r] = a2[r] + res[r];
  __syncthreads();                              // 4: all P reads done
  // O = y into A edge half as f32, XOR swizzle c^((row&7)<<2)
  #pragma unroll
  for (int r = 0; r < 16; ++r) {
    int row = (r & 3) + 8 * (r >> 2) + 4 * half;
    if (row < KNN)
      Af[row * 256 + 128 + (col ^ ((row & 7) << 2))] = y[r];
  }
  __syncthreads();                              // 5: O ready
  // stats: 8 threads per row, 16 cols each, 3-level shfl
  {
    int srow = t >> 3, sub = t & 7;
    if (srow < KNN) {
      float s = 0.f, q = 0.f;
      #pragma unroll
      for (int qd = 0; qd < 4; ++qd) {
        int c0 = (sub * 16 + qd * 4) ^ ((srow & 7) << 2);
        float4 v = *(const float4*)(Af + srow * 256 + 128 + c0);
        s += v.x + v.y + v.z + v.w;
        q = fmaf(v.x, v.x, q); q = fmaf(v.y, v.y, q);
        q = fmaf(v.z, v.z, q); q = fmaf(v.w, v.w, q);
      }
      #pragma unroll
      for (int off = 1; off < 8; off <<= 1) {
        s += __shfl_xor(s, off);
        q += __shfl_xor(q, off);
      }
      if (sub == 0) {
        float mean = s * (1.f / (float)H);
        mv[srow] = mean;
        rs[srow] = rsqrtf(q * (1.f / (float)H) - mean * mean + EPSV);
      }
    }
  }
  __syncthreads();                              // 6: stats ready, O reads done
  // normalize; optional global store; write new edges into A edge half
  {
    float gv = ge[col], bbv = gbb[col];
    #pragma unroll
    for (int r = 0; r < 16; r += 2) {
      int row0 = (r & 3) + 8 * (r >> 2) + 4 * half;
      if (row0 < KNN) {
        float o0 = (y[r]     - mv[row0])     * rs[row0]     * gv + bbv;
        float o1 = (y[r + 1] - mv[row0 + 1]) * rs[row0 + 1] * gv + bbv;
        u32 hp = pk2(o0, o1);
        float l0 = o0 - __uint_as_float(hp << 16);
        float l1 = o1 - __uint_as_float(hp & 0xffff0000u);
        u32 lp = pk2(l0, l1);
        if (writeEdges) {
          size_t b0 = ((size_t)n * KNN + row0) * 256 + pko(col);
          edges_pk[b0]            = (u16)hp;
          edges_pk[b0 + 16]       = (u16)lp;
          edges_pk[b0 + 256]      = (u16)(hp >> 16);
          edges_pk[b0 + 256 + 16] = (u16)(lp >> 16);
        }
        A[axi(row0, coff)]          = (u16)hp;
        A[axi(row0, coff + 16)]     = (u16)lp;
        A[axi(row0 + 1, coff)]      = (u16)(hp >> 16);
        A[axi(row0 + 1, coff + 16)] = (u16)(lp >> 16);
      }
    }
  }
  __syncthreads();                              // 7: A = [nbr | new edges]
  // message MLP1 on updated A
  f32x16 macc = mlp1_mfma(A, pkMW1 + (size_t)(w * 16) * 1024, spm, l);
  float ss = 0.f;
  #pragma unroll
  for (int r = 0; r < 16; ++r) {
    float v = fmaxf(macc[r], 0.f);
    if (r >= 14) v = half ? 0.f : v;
    ss += v;
  }
  ss += __shfl_xor(ss, 32);
  if (l < 32) hsum[w * 32 + l] = ss;
  __syncthreads();                              // 8: hsum ready
  if (t < H) {
    float a2m = 0.f;
    for (int k = 0; k < H; k += 4) {
      float4 hv = *(const float4*)(hsum + k);
      a2m = fmaf(hv.x, mW2[(k + 0) * H + t], a2m);
      a2m = fmaf(hv.y, mW2[(k + 1) * H + t], a2m);
      a2m = fmaf(hv.z, mW2[(k + 2) * H + t], a2m);
      a2m = fmaf(hv.w, mW2[(k + 3) * H + t], a2m);
    }
    agg[(size_t)n * H + t] = a2m + (float)KNN * mb2[t];
  }
}

// ---------------- output ----------------

__global__ __launch_bounds__(64) void out_kernel(
    const float* __restrict__ nodes, const float* __restrict__ Wout,
    const float* __restrict__ bout, float* __restrict__ out)
{
  __shared__ float x[H];
  int n = blockIdx.x, t = threadIdx.x;
  x[t] = nodes[(size_t)n * H + t];
  x[64 + t] = nodes[(size_t)n * H + 64 + t];
  __syncthreads();
  if (t < AOUT) {
    float acc = bout[t];
    for (int hh = 0; hh < H; ++hh)
      acc = fmaf(x[hh], Wout[hh * AOUT + t], acc);
    out[n * AOUT + t] = acc;
  }
}

// ---------------- launch ----------------

extern "C" void kernel_launch(void* const* d_in, const int* in_sizes, int n_in,
                              void* d_out, int out_size, void* d_ws, size_t ws_size,
                              hipStream_t stream) {
  const float* nf    = (const float*)d_in[0];
  const float* ef    = (const float*)d_in[1];
  const int*   knn   = (const int*)  d_in[2];
  const float* Wn    = (const float*)d_in[3];
  const float* bn    = (const float*)d_in[4];
  const float* We    = (const float*)d_in[5];
  const float* be    = (const float*)d_in[6];
  const float* mW1   = (const float*)d_in[7];
  const float* mb1   = (const float*)d_in[8];
  const float* mW2   = (const float*)d_in[9];
  const float* mb2   = (const float*)d_in[10];
  const float* nW1   = (const float*)d_in[11];
  const float* nb1   = (const float*)d_in[12];
  const float* nW2   = (const float*)d_in[13];
  const float* nb2   = (const float*)d_in[14];
  const float* eW1   = (const float*)d_in[15];
  const float* eb1   = (const float*)d_in[16];
  const float* eW2   = (const float*)d_in[17];
  const float* eb2   = (const float*)d_in[18];
  const float* gn    = (const float*)d_in[19];
  const float* bnrm  = (const float*)d_in[20];
  const float* ge    = (const float*)d_in[21];
  const float* benrm = (const float*)d_in[22];
  const float* Wout  = (const float*)d_in[23];
  const float* bout  = (const float*)d_in[24];
  float* out = (float*)d_out;

  float* ws     = (float*)d_ws;
  float* nodes  = ws;                                  // N*H f32
  float* aggse  = ws + (size_t)NN * H;                 // N*H f32: agg, aliased by sp_e
  float* sp_m   = ws + (size_t)2 * NN * H;             // N*H f32
  u16* nodes_pk = (u16*)(ws + (size_t)3 * NN * H);     // N*256 u16
  u16* edges_pk = nodes_pk + (size_t)NN * 256;         // N*K*256 u16 (307 MB)
  u16* pk       = edges_pk + (size_t)NN * KNN * 256;   // packed weights
  u16* pkWe = pk;                       // 4*15*2*512 = 61440
  u16* pkM1 = pkWe + 61440;             // 3 x 65536
  u16* pkE1 = pkM1 + 3 * 65536;         // 3 x 65536
  u16* pkE2 = pkE1 + 3 * 65536;         // 3 x 32768
  float* sp_e = aggse;                  // alias: per-block read(sp_e)->write(agg) is safe

  node_init_kernel<<<(NN * H + 255) / 256, 256, 0, stream>>>(nf, Wn, bn, nodes, nodes_pk);
  repack_w<<<15, 256, 0, stream>>>(We, pkWe, 15);
  for (int l = 0; l < NL; ++l) {
    repack_w<<<16, 256, 0, stream>>>(mW1 + (size_t)l * CIN * H + 128 * H, pkM1 + l * 65536, 16);
    repack_w<<<16, 256, 0, stream>>>(eW1 + (size_t)l * CIN * H + 128 * H, pkE1 + l * 65536, 16);
    repack_w<<<8,  256, 0, stream>>>(eW2 + (size_t)l * H * H,             pkE2 + l * 32768, 8);
  }
  edge_init_mfma<<<NN * KNN / 32, 256, 0, stream>>>(ef, pkWe, be, edges_pk);

  // layer-0 message pass (standalone)
  sp_kernel<<<NN / 2, 256, 0, stream>>>(nodes, mW1, mb1, sp_m);
  msg_agg_mfma<<<NN, 256, 0, stream>>>(nodes_pk, edges_pk, knn, sp_m,
      pkM1, mW2, mb2, aggse);

  for (int l = 0; l < NL; ++l) {
    const float* mW1n = (l < 2) ? mW1 + (size_t)(l + 1) * CIN * H : mW1;
    const float* mb1n = (l < 2) ? mb1 + (size_t)(l + 1) * H       : mb1;
    node_upd2_kernel<<<NN, 128, 0, stream>>>(nodes, aggse,
        nW1 + (size_t)l * 2 * H * H, nb1 + l * H,
        nW2 + (size_t)l * H * H, nb2 + l * H,
        gn + l * H, bnrm + l * H, nodes_pk,
        eW1 + (size_t)l * CIN * H, eb1 + l * H, sp_e,
        mW1n, mb1n, sp_m);
    if (l < 2) {
      fused_edge_msg<<<NN, 256, 0, stream>>>(nodes_pk, edges_pk, knn,
          sp_e, sp_m,
          pkE1 + l * 65536, pkE2 + l * 32768, eb2 + l * H,
          ge + l * H, benrm + l * H,
          pkM1 + (l + 1) * 65536, mW2 + (size_t)(l + 1) * H * H,
          mb2 + (l + 1) * H, aggse, (l == 0) ? 1 : 0);
    }
  }
  out_kernel<<<NN, 64, 0, stream>>>(nodes, Wout, bout, out);
}

// Round 11
// 1562.071 us; speedup vs baseline: 1.6798x; 1.3247x over previous
//
#include <hip/hip_runtime.h>

// InverseFoldingModel: 3-layer message-passing GNN, MFMA bf16 hi/lo (2-term).
// R11 = R10 + batched-MFMA node update (replaces per-node VALU node_upd2 + folds
// sp_e/sp_m GEMMs in-block) + single repack_many launch.

#define NN   20000
#define KNN  30
#define H    128
#define EIN  240
#define NL   3
#define AOUT 20
#define CIN  384   // 2H + E
#define EPSV 1e-5f

typedef unsigned short u16;
typedef unsigned int   u32;
typedef float f32x16 __attribute__((ext_vector_type(16)));
typedef short s16x8  __attribute__((ext_vector_type(8)));
typedef short s16x4  __attribute__((ext_vector_type(4)));

#define MFMA32(acc, a, b) \
  asm("v_mfma_f32_32x32x16_bf16 %0, %1, %2, %0" : "+v"(acc) : "v"(a), "v"(b))

__device__ __forceinline__ u16 bh(float x) {           // f32 -> bf16 (RNE)
  u32 u = __float_as_uint(x);
  u += 0x7fffu + ((u >> 16) & 1u);
  return (u16)(u >> 16);
}
__device__ __forceinline__ float hf(u16 h) { return __uint_as_float(((u32)h) << 16); }
// packed 2x f32 -> 2x bf16 (lo16 = a, hi16 = b)
__device__ __forceinline__ u32 pk2(float a, float b) {
  u32 r; asm("v_cvt_pk_bf16_f32 %0, %1, %2" : "=v"(r) : "v"(a), "v"(b)); return r;
}

// packed-row layout: 128 elems -> 8 chunks x (16 hi u16 + 16 lo u16) = 256 u16
__device__ __forceinline__ int pko(int col) { return ((col >> 4) << 5) + (col & 15); }

// XOR-swizzled LDS index (u16 units); swizzle: byte ^= (row&7)<<4
__device__ __forceinline__ int axi(int row, int off) { return (row * 512 + off) ^ ((row & 7) << 3); }

// write 4 consecutive logical-k elements as hi4+lo4 (f32 source)
__device__ __forceinline__ void wrA4(u16* A, int row, int off, float4 v) {
  u16 h0 = bh(v.x), h1 = bh(v.y), h2 = bh(v.z), h3 = bh(v.w);
  s16x4 hv = { (short)h0, (short)h1, (short)h2, (short)h3 };
  s16x4 lv = { (short)bh(v.x - hf(h0)), (short)bh(v.y - hf(h1)),
               (short)bh(v.z - hf(h2)), (short)bh(v.w - hf(h3)) };
  *(s16x4*)(A + axi(row, off))      = hv;
  *(s16x4*)(A + axi(row, off + 16)) = lv;
}

// ---------------- weight repack (single launch) ----------------
// arena offsets (u16): pkWe 0 | pkM1 61440 | pkE1 258048 | pkE2 454656 |
// pkN1 552960 | pkN2 749568 | pkE1s 847872 | pkM1s 913408
#define PK_WE   0
#define PK_M1   61440
#define PK_E1   258048
#define PK_E2   454656
#define PK_N1   552960
#define PK_N2   749568
#define PK_E1S  847872
#define PK_M1S  913408

__global__ __launch_bounds__(256) void repack_many(
    const float* __restrict__ We, const float* __restrict__ mW1,
    const float* __restrict__ eW1, const float* __restrict__ eW2,
    const float* __restrict__ nW1, const float* __restrict__ nW2,
    u16* __restrict__ pk)
{
  int b = blockIdx.x;
  const float* W; u16* dst; int nS, s;
  if (b < 15)              { W = We; dst = pk + PK_WE; nS = 15; s = b; }
  else if ((b -= 15) < 48) { int l = b >> 4; s = b & 15; nS = 16;
                             W = mW1 + (size_t)l * CIN * H + 128 * H; dst = pk + PK_M1 + l * 65536; }
  else if ((b -= 48) < 48) { int l = b >> 4; s = b & 15; nS = 16;
                             W = eW1 + (size_t)l * CIN * H + 128 * H; dst = pk + PK_E1 + l * 65536; }
  else if ((b -= 48) < 24) { int l = b >> 3; s = b & 7; nS = 8;
                             W = eW2 + (size_t)l * H * H; dst = pk + PK_E2 + l * 32768; }
  else if ((b -= 24) < 48) { int l = b >> 4; s = b & 15; nS = 16;
                             W = nW1 + (size_t)l * 2 * H * H; dst = pk + PK_N1 + l * 65536; }
  else if ((b -= 48) < 24) { int l = b >> 3; s = b & 7; nS = 8;
                             W = nW2 + (size_t)l * H * H; dst = pk + PK_N2 + l * 32768; }
  else if ((b -= 24) < 16) { int l = b >> 3; s = b & 7; nS = 8;     // eW1 src rows, l=0,1
                             W = eW1 + (size_t)l * CIN * H; dst = pk + PK_E1S + l * 32768; }
  else { b -= 16;            int l = b >> 3; s = b & 7; nS = 8;     // mW1 src rows, layers 1,2
                             W = mW1 + (size_t)(l + 1) * CIN * H; dst = pk + PK_M1S + l * 32768; }
  int t = threadIdx.x;
  int c = t >> 6, ln = t & 63;
  int col = c * 32 + (ln & 31);
  int kb  = s * 16 + (ln >> 5) * 8;
  size_t base = ((size_t)(c * nS + s) * 2) * 512 + ln * 8;
  #pragma unroll
  for (int i = 0; i < 8; ++i) {
    float v = W[(size_t)(kb + i) * H + col];
    u16 hi = bh(v);
    dst[base + i]       = hi;
    dst[base + 512 + i] = bh(v - hf(hi));
  }
}

// ---------------- init ----------------

__global__ __launch_bounds__(256) void node_init_kernel(
    const float* __restrict__ nf, const float* __restrict__ Wn,
    const float* __restrict__ bn, float* __restrict__ nodes,
    u16* __restrict__ nodes_pk)
{
  int tid = blockIdx.x * 256 + threadIdx.x;
  if (tid >= NN * H) return;
  int n = tid >> 7, h = tid & (H - 1);
  float acc = bn[h];
  #pragma unroll
  for (int i = 0; i < 6; ++i)
    acc = fmaf(nf[n * 6 + i], Wn[i * H + h], acc);
  nodes[tid] = acc;
  u16 hi = bh(acc);
  nodes_pk[(size_t)n * 256 + pko(h)]      = hi;
  nodes_pk[(size_t)n * 256 + pko(h) + 16] = bh(acc - hf(hi));
}

// edges = ef @ We + be (K=240 -> 15 chunks), packed hi/lo output
__global__ __launch_bounds__(256) void edge_init_mfma(
    const float* __restrict__ ef, const u16* __restrict__ pkWe,
    const float* __restrict__ be, u16* __restrict__ edges_pk)
{
  __shared__ __align__(16) u16 A[32 * 512];
  int r0 = blockIdx.x * 32, t = threadIdx.x;
  for (int u = t; u < 1920; u += 256) {
    int r = u & 31, c = u >> 5;                   // c 0..59
    int k = c * 4;
    float4 v = *(const float4*)(ef + (size_t)(r0 + r) * EIN + k);
    wrA4(A, r, (k >> 4) * 32 + (k & 15), v);
  }
  __syncthreads();
  int w = t >> 6, l = t & 63;
  int lane31 = l & 31, half = l >> 5;
  float bev = be[w * 32 + lane31];
  f32x16 acc;
  #pragma unroll
  for (int r = 0; r < 16; ++r) acc[r] = bev;
  #pragma unroll
  for (int s = 0; s < 15; ++s) {
    s16x8 ah = *(const s16x8*)(A + axi(lane31, s * 32 + half * 8));
    s16x8 al = *(const s16x8*)(A + axi(lane31, s * 32 + 16 + half * 8));
    const u16* pb = pkWe + (size_t)((w * 15 + s) * 2) * 512 + l * 8;
    s16x8 bhv = *(const s16x8*)(pb);
    MFMA32(acc, ah, bhv);
    MFMA32(acc, al, bhv);
  }
  int col = w * 32 + lane31;
  #pragma unroll
  for (int r = 0; r < 16; ++r) {
    int row = (r & 3) + 8 * (r >> 2) + 4 * half;
    float v = acc[r];
    u16 hi = bh(v);
    size_t base = (size_t)(r0 + row) * 256 + pko(col);
    edges_pk[base]      = hi;
    edges_pk[base + 16] = bh(v - hf(hi));
  }
}

// ---------------- shared pieces ----------------

// copy-staging: A rows 0..29 = [nbr_pk row | edge_pk row]; rows 30,31 untouched.
__device__ __forceinline__ void stage_copy(
    const u16* __restrict__ nodes_pk, const u16* __restrict__ edges_pk,
    const int* __restrict__ knn, int n, int t, u16* A)
{
  int w = t >> 6, l = t & 63;
  int sub = l >> 5;
  int off = (l & 31) * 8;
  #pragma unroll
  for (int j = 0; j < 8; ++j) {
    int task = w * 16 + j * 2 + sub;
    int row  = task & 31;
    int part = task >> 5;           // 0 = nbr, 1 = edge
    if (row < KNN) {
      const u16* src = (part == 0)
        ? nodes_pk + (size_t)knn[n * KNN + row] * 256 + off
        : edges_pk + ((size_t)n * KNN + row) * 256 + off;
      s16x8 v = *(const s16x8*)src;
      *(s16x8*)(A + ((row * 512 + part * 256 + off) ^ ((row & 7) << 3))) = v;
    }
  }
}

// MLP1: acc = bias/sp (broadcast over rows) + A @ Wbc, K=256; 2-term (a_hi+a_lo)xW_hi
__device__ __forceinline__ f32x16 mlp1_mfma(
    const u16* A, const u16* __restrict__ pk, float spv, int l)
{
  int lane31 = l & 31, half = l >> 5;
  f32x16 acc;
  #pragma unroll
  for (int r = 0; r < 16; ++r) acc[r] = spv;
  #pragma unroll
  for (int s = 0; s < 16; ++s) {
    s16x8 ah = *(const s16x8*)(A + axi(lane31, s * 32 + half * 8));
    s16x8 al = *(const s16x8*)(A + axi(lane31, s * 32 + 16 + half * 8));
    const u16* pb = pk + (size_t)(s * 2) * 512 + l * 8;
    s16x8 bhv = *(const s16x8*)(pb);
    MFMA32(acc, ah, bhv);
    MFMA32(acc, al, bhv);
  }
  return acc;
}

// sp = nodes @ W[0:128] + b  (layer-0 message path only, initial nodes, f32)
__global__ __launch_bounds__(256) void sp_kernel(
    const float* __restrict__ nodes, const float* __restrict__ W,
    const float* __restrict__ b, float* __restrict__ sp)
{
  __shared__ __align__(16) float xl[2][H];
  int n0 = blockIdx.x * 2, t = threadIdx.x;
  int row = t >> 7, col = t & (H - 1);
  xl[row][col] = nodes[(size_t)(n0 + row) * H + col];
  __syncthreads();
  float acc = b[col];
  for (int k = 0; k < H; k += 4) {
    float4 xv = *(const float4*)(&xl[row][k]);
    acc = fmaf(xv.x, W[(k + 0) * H + col], acc);
    acc = fmaf(xv.y, W[(k + 1) * H + col], acc);
    acc = fmaf(xv.z, W[(k + 2) * H + col], acc);
    acc = fmaf(xv.w, W[(k + 3) * H + col], acc);
  }
  sp[(size_t)(n0 + row) * H + col] = acc;
}

// ---------------- per-layer kernels ----------------

__global__ __launch_bounds__(256) void msg_agg_mfma(
    const u16* __restrict__ nodes_pk, const u16* __restrict__ edges_pk,
    const int* __restrict__ knn, const float* __restrict__ sp,
    const u16* __restrict__ pkW1, const float* __restrict__ W2,
    const float* __restrict__ b2, float* __restrict__ agg)
{
  __shared__ __align__(16) u16 A[32 * 512];     // rows 30,31 = pad; hsum aliases row 30
  float* hsum = (float*)(A + 30 * 512);         // 128 f32
  int n = blockIdx.x, t = threadIdx.x;
  stage_copy(nodes_pk, edges_pk, knn, n, t, A);
  int w = t >> 6, l = t & 63;
  int lane31 = l & 31, half = l >> 5;
  float spv = sp[(size_t)n * H + w * 32 + lane31];
  __syncthreads();
  f32x16 acc = mlp1_mfma(A, pkW1 + (size_t)(w * 16) * 1024, spv, l);
  float ss = 0.f;
  #pragma unroll
  for (int r = 0; r < 16; ++r) {
    float v = fmaxf(acc[r], 0.f);
    if (r >= 14) v = half ? 0.f : v;           // mask pad rows 30,31
    ss += v;
  }
  ss += __shfl_xor(ss, 32);
  if (l < 32) hsum[w * 32 + l] = ss;
  __syncthreads();
  if (t < H) {
    float a2 = 0.f;
    for (int k = 0; k < H; k += 4) {
      float4 hv = *(const float4*)(hsum + k);
      a2 = fmaf(hv.x, W2[(k + 0) * H + t], a2);
      a2 = fmaf(hv.y, W2[(k + 1) * H + t], a2);
      a2 = fmaf(hv.z, W2[(k + 2) * H + t], a2);
      a2 = fmaf(hv.w, W2[(k + 3) * H + t], a2);
    }
    agg[(size_t)n * H + t] = a2 + (float)KNN * b2[t];
  }
}

// batched node update via MFMA: 32 nodes/block (625 blocks).
// A = [nodes hi/lo (chunks 0-7) | agg hi/lo (chunks 8-15)] -> MLP1(K=256) -> relu
// -> P in agg half -> MLP2(K=128) -> +res -> LN (O in nodes half, mv/rs row0 agg)
// -> nodes/nodes_pk; LN_out hi/lo back into agg half -> sp_e/sp_m GEMMs (K=128).
__global__ __launch_bounds__(256) void node_upd_mfma(
    float* __restrict__ nodes, const float* __restrict__ agg,
    u16* __restrict__ nodes_pk,
    const u16* __restrict__ pkW1, const float* __restrict__ b1,
    const u16* __restrict__ pkW2, const float* __restrict__ b2,
    const float* __restrict__ g, const float* __restrict__ bb,
    const u16* __restrict__ pkE1s, const float* __restrict__ eb1,
    float* __restrict__ sp_e,
    const u16* __restrict__ pkM1s, const float* __restrict__ mb1,
    float* __restrict__ sp_m, int doSp)
{
  __shared__ __align__(16) u16 A[32 * 512];     // 32 KB, all scratch aliased inside
  float* Af = (float*)A;
  float* mv = Af + 128;                         // row-0 agg half (dead P region)
  float* rs = Af + 160;
  int n0 = blockIdx.x * 32, t = threadIdx.x;
  int w = t >> 6, lane = t & 63;
  int lane31 = lane & 31, half = lane >> 5;
  int col = w * 32 + lane31;
  int coff = 256 + pko(col);
  // stage: tasks 0-31 copy nodes_pk rows; tasks 32-63 convert agg rows (f32->hi/lo)
  {
    int sub = lane >> 5;
    int off = (lane & 31) * 8;
    #pragma unroll
    for (int j = 0; j < 8; ++j) {
      int task = w * 16 + j * 2 + sub;
      int row = task & 31;
      if (task < 32) {
        s16x8 v = *(const s16x8*)(nodes_pk + (size_t)(n0 + row) * 256 + off);
        *(s16x8*)(A + ((row * 512 + off) ^ ((row & 7) << 3))) = v;
      } else {
        int k = (lane & 31) * 4;
        float4 v = *(const float4*)(agg + (size_t)(n0 + row) * H + k);
        wrA4(A, row, 256 + ((k >> 4) << 5) + (k & 15), v);
      }
    }
  }
  float b1v = b1[col];
  __syncthreads();                              // 1: A staged
  f32x16 acc = mlp1_mfma(A, pkW1 + (size_t)(w * 16) * 1024, b1v, lane);
  // residual = nodes hi+lo from A nodes half
  float res[16];
  #pragma unroll
  for (int r = 0; r < 16; ++r) {
    int row = (r & 3) + 8 * (r >> 2) + 4 * half;
    res[r] = hf(A[axi(row, pko(col))]) + hf(A[axi(row, pko(col) + 16)]);
  }
  __syncthreads();                              // 2: all A reads done
  // P = relu(acc) hi/lo into agg half
  #pragma unroll
  for (int r = 0; r < 16; r += 2) {
    int row0 = (r & 3) + 8 * (r >> 2) + 4 * half;
    float v0 = fmaxf(acc[r], 0.f), v1 = fmaxf(acc[r + 1], 0.f);
    u32 hp = pk2(v0, v1);
    float l0 = v0 - __uint_as_float(hp << 16);
    float l1 = v1 - __uint_as_float(hp & 0xffff0000u);
    u32 lp = pk2(l0, l1);
    A[axi(row0, coff)]          = (u16)hp;
    A[axi(row0, coff + 16)]     = (u16)lp;
    A[axi(row0 + 1, coff)]      = (u16)(hp >> 16);
    A[axi(row0 + 1, coff + 16)] = (u16)(lp >> 16);
  }
  __syncthreads();                              // 3: P ready
  float b2v = b2[col];
  f32x16 a2;
  #pragma unroll
  for (int r = 0; r < 16; ++r) a2[r] = b2v;
  #pragma unroll
  for (int s = 0; s < 8; ++s) {
    s16x8 ah = *(const s16x8*)(A + axi(lane31, 256 + s * 32 + half * 8));
    s16x8 al = *(const s16x8*)(A + axi(lane31, 256 + s * 32 + 16 + half * 8));
    const u16* pb = pkW2 + (size_t)((w * 8 + s) * 2) * 512 + lane * 8;
    s16x8 bhv = *(const s16x8*)(pb);
    MFMA32(a2, ah, bhv);
    MFMA32(a2, al, bhv);
  }
  float y[16];
  #pragma unroll
  for (int r = 0; r < 16; ++r) y[r] = a2[r] + res[r];
  __syncthreads();                              // 4: all P reads done
  // O = y f32 into nodes half, XOR swizzle
  #pragma unroll
  for (int r = 0; r < 16; ++r) {
    int row = (r & 3) + 8 * (r >> 2) + 4 * half;
    Af[row * 256 + (col ^ ((row & 7) << 2))] = y[r];
  }
  __syncthreads();                              // 5: O ready
  // stats: 8 threads per row x 32 rows = 256 threads
  {
    int srow = t >> 3, sub2 = t & 7;
    float s = 0.f, q = 0.f;
    #pragma unroll
    for (int qd = 0; qd < 4; ++qd) {
      int c0 = (sub2 * 16 + qd * 4) ^ ((srow & 7) << 2);
      float4 v = *(const float4*)(Af + srow * 256 + c0);
      s += v.x + v.y + v.z + v.w;
      q = fmaf(v.x, v.x, q); q = fmaf(v.y, v.y, q);
      q = fmaf(v.z, v.z, q); q = fmaf(v.w, v.w, q);
    }
    #pragma unroll
    for (int o2 = 1; o2 < 8; o2 <<= 1) {
      s += __shfl_xor(s, o2);
      q += __shfl_xor(q, o2);
    }
    if (sub2 == 0) {
      float mean = s * (1.f / (float)H);
      mv[srow] = mean;
      rs[srow] = rsqrtf(q * (1.f / (float)H) - mean * mean + EPSV);
    }
  }
  __syncthreads();                              // 6: stats ready
  // normalize into regs (reads mv/rs only)
  float gv = g[col], bbv = bb[col];
  #pragma unroll
  for (int r = 0; r < 16; ++r) {
    int row = (r & 3) + 8 * (r >> 2) + 4 * half;
    y[r] = (y[r] - mv[row]) * rs[row] * gv + bbv;
  }
  __syncthreads();                              // 7: mv/rs reads done (agg half reusable)
  // write nodes + nodes_pk; stash LN_out hi/lo into agg half for sp GEMMs
  #pragma unroll
  for (int r = 0; r < 16; r += 2) {
    int row0 = (r & 3) + 8 * (r >> 2) + 4 * half;
    float o0 = y[r], o1 = y[r + 1];
    nodes[(size_t)(n0 + row0) * H + col]     = o0;
    nodes[(size_t)(n0 + row0 + 1) * H + col] = o1;
    u32 hp = pk2(o0, o1);
    float l0 = o0 - __uint_as_float(hp << 16);
    float l1 = o1 - __uint_as_float(hp & 0xffff0000u);
    u32 lp = pk2(l0, l1);
    size_t b0 = (size_t)(n0 + row0) * 256 + pko(col);
    nodes_pk[b0]            = (u16)hp;
    nodes_pk[b0 + 16]       = (u16)lp;
    nodes_pk[b0 + 256]      = (u16)(hp >> 16);
    nodes_pk[b0 + 256 + 16] = (u16)(lp >> 16);
    A[axi(row0, coff)]          = (u16)hp;
    A[axi(row0, coff + 16)]     = (u16)lp;
    A[axi(row0 + 1, coff)]      = (u16)(hp >> 16);
    A[axi(row0 + 1, coff + 16)] = (u16)(lp >> 16);
  }
  if (doSp) {
    __syncthreads();                            // 8: LN_out in agg half
    float ebv = eb1[col], mbv = mb1[col];
    f32x16 aE, aM;
    #pragma unroll
    for (int r = 0; r < 16; ++r) { aE[r] = ebv; aM[r] = mbv; }
    #pragma unroll
    for (int s = 0; s < 8; ++s) {
      s16x8 ah = *(const s16x8*)(A + axi(lane31, 256 + s * 32 + half * 8));
      s16x8 al = *(const s16x8*)(A + axi(lane31, 256 + s * 32 + 16 + half * 8));
      const u16* pbE = pkE1s + (size_t)((w * 8 + s) * 2) * 512 + lane * 8;
      const u16* pbM = pkM1s + (size_t)((w * 8 + s) * 2) * 512 + lane * 8;
      s16x8 bE = *(const s16x8*)(pbE);
      s16x8 bM = *(const s16x8*)(pbM);
      MFMA32(aE, ah, bE);
      MFMA32(aE, al, bE);
      MFMA32(aM, ah, bM);
      MFMA32(aM, al, bM);
    }
    #pragma unroll
    for (int r = 0; r < 16; ++r) {
      int row = (r & 3) + 8 * (r >> 2) + 4 * half;
      sp_e[(size_t)(n0 + row) * H + col] = aE[r];
      sp_m[(size_t)(n0 + row) * H + col] = aM[r];
    }
  }
}

// fused: edge_upd(l) + msg_agg(l+1). All scratch inside A (32 KB).
__global__ __launch_bounds__(256) void fused_edge_msg(
    const u16* __restrict__ nodes_pk, u16* __restrict__ edges_pk,
    const int* __restrict__ knn,
    const float* __restrict__ sp_e, const float* __restrict__ sp_m,
    const u16* __restrict__ pkEW1, const u16* __restrict__ pkEW2,
    const float* __restrict__ eb2, const float* __restrict__ ge,
    const float* __restrict__ gbb,
    const u16* __restrict__ pkMW1, const float* __restrict__ mW2,
    const float* __restrict__ mb2, float* __restrict__ agg,
    int writeEdges)
{
  __shared__ __align__(16) u16 A[32 * 512];     // 32 KB total
  float* hsum = (float*)(A + 30 * 512);         // 128 f32 (pad row 30, nbr half)
  float* mv   = (float*)(A + 31 * 512);         // 32 f32 (pad row 31, nbr half)
  float* rs   = mv + 32;                        // 32 f32
  float* Af   = (float*)A;

  int n = blockIdx.x, t = threadIdx.x;
  stage_copy(nodes_pk, edges_pk, knn, n, t, A);
  int w = t >> 6, l = t & 63;
  int lane31 = l & 31, half = l >> 5;
  int col = w * 32 + lane31;
  float spe = sp_e[(size_t)n * H + col];
  float spm = sp_m[(size_t)n * H + col];
  int coff = 256 + pko(col);
  __syncthreads();                              // 1: A staged
  f32x16 acc = mlp1_mfma(A, pkEW1 + (size_t)(w * 16) * 1024, spe, l);
  float res[16];
  #pragma unroll
  for (int r = 0; r < 16; ++r) {
    int row = (r & 3) + 8 * (r >> 2) + 4 * half;
    res[r] = (row < KNN)
      ? hf(A[axi(row, coff)]) + hf(A[axi(row, coff + 16)]) : 0.f;
  }
  __syncthreads();                              // 2: all A-edge reads done
  #pragma unroll
  for (int r = 0; r < 16; r += 2) {
    int row0 = (r & 3) + 8 * (r >> 2) + 4 * half;
    if (row0 < KNN) {
      float v0 = fmaxf(acc[r], 0.f), v1 = fmaxf(acc[r + 1], 0.f);
      u32 hp = pk2(v0, v1);
      float l0 = v0 - __uint_as_float(hp << 16);
      float l1 = v1 - __uint_as_float(hp & 0xffff0000u);
      u32 lp = pk2(l0, l1);
      A[axi(row0, coff)]          = (u16)hp;
      A[axi(row0, coff + 16)]     = (u16)lp;
      A[axi(row0 + 1, coff)]      = (u16)(hp >> 16);
      A[axi(row0 + 1, coff + 16)] = (u16)(lp >> 16);
    }
  }
  __syncthreads();                              // 3: P ready
  float b2v = eb2[col];
  f32x16 a2;
  #pragma unroll
  for (int r = 0; r < 16; ++r) a2[r] = b2v;
  #pragma unroll
  for (int s = 0; s < 8; ++s) {
    s16x8 ah = *(const s16x8*)(A + axi(lane31, 256 + s * 32 + half * 8));
    s16x8 al = *(const s16x8*)(A + axi(lane31, 256 + s * 32 + 16 + half * 8));
    const u16* pb = pkEW2 + (size_t)((w * 8 + s) * 2) * 512 + l * 8;
    s16x8 bhv = *(const s16x8*)(pb);
    MFMA32(a2, ah, bhv);
    MFMA32(a2, al, bhv);
  }
  float y[16];
  #pragma unroll
  for (int r = 0; r < 16; ++r) y[r] = a2[r] + res[r];
  __syncthreads();                              // 4: all P reads done
  #pragma unroll
  for (int r = 0; r < 16; ++r) {
    int row = (r & 3) + 8 * (r >> 2) + 4 * half;
    if (row < KNN)
      Af[row * 256 + 128 + (col ^ ((row & 7) << 2))] = y[r];
  }
  __syncthreads();                              // 5: O ready
  {
    int srow = t >> 3, sub = t & 7;
    if (srow < KNN) {
      float s = 0.f, q = 0.f;
      #pragma unroll
      for (int qd = 0; qd < 4; ++qd) {
        int c0 = (sub * 16 + qd * 4) ^ ((srow & 7) << 2);
        float4 v = *(const float4*)(Af + srow * 256 + 128 + c0);
        s += v.x + v.y + v.z + v.w;
        q = fmaf(v.x, v.x, q); q = fmaf(v.y, v.y, q);
        q = fmaf(v.z, v.z, q); q = fmaf(v.w, v.w, q);
      }
      #pragma unroll
      for (int off = 1; off < 8; off <<= 1) {
        s += __shfl_xor(s, off);
        q += __shfl_xor(q, off);
      }
      if (sub == 0) {
        float mean = s * (1.f / (float)H);
        mv[srow] = mean;
        rs[srow] = rsqrtf(q * (1.f / (float)H) - mean * mean + EPSV);
      }
    }
  }
  __syncthreads();                              // 6: stats ready
  {
    float gv = ge[col], bbv = gbb[col];
    #pragma unroll
    for (int r = 0; r < 16; r += 2) {
      int row0 = (r & 3) + 8 * (r >> 2) + 4 * half;
      if (row0 < KNN) {
        float o0 = (y[r]     - mv[row0])     * rs[row0]     * gv + bbv;
        float o1 = (y[r + 1] - mv[row0 + 1]) * rs[row0 + 1] * gv + bbv;
        u32 hp = pk2(o0, o1);
        float l0 = o0 - __uint_as_float(hp << 16);
        float l1 = o1 - __uint_as_float(hp & 0xffff0000u);
        u32 lp = pk2(l0, l1);
        if (writeEdges) {
          size_t b0 = ((size_t)n * KNN + row0) * 256 + pko(col);
          edges_pk[b0]            = (u16)hp;
          edges_pk[b0 + 16]       = (u16)lp;
          edges_pk[b0 + 256]      = (u16)(hp >> 16);
          edges_pk[b0 + 256 + 16] = (u16)(lp >> 16);
        }
        A[axi(row0, coff)]          = (u16)hp;
        A[axi(row0, coff + 16)]     = (u16)lp;
        A[axi(row0 + 1, coff)]      = (u16)(hp >> 16);
        A[axi(row0 + 1, coff + 16)] = (u16)(lp >> 16);
      }
    }
  }
  __syncthreads();                              // 7: A = [nbr | new edges]
  f32x16 macc = mlp1_mfma(A, pkMW1 + (size_t)(w * 16) * 1024, spm, l);
  float ss = 0.f;
  #pragma unroll
  for (int r = 0; r < 16; ++r) {
    float v = fmaxf(macc[r], 0.f);
    if (r >= 14) v = half ? 0.f : v;
    ss += v;
  }
  ss += __shfl_xor(ss, 32);
  if (l < 32) hsum[w * 32 + l] = ss;
  __syncthreads();                              // 8: hsum ready
  if (t < H) {
    float a2m = 0.f;
    for (int k = 0; k < H; k += 4) {
      float4 hv = *(const float4*)(hsum + k);
      a2m = fmaf(hv.x, mW2[(k + 0) * H + t], a2m);
      a2m = fmaf(hv.y, mW2[(k + 1) * H + t], a2m);
      a2m = fmaf(hv.z, mW2[(k + 2) * H + t], a2m);
      a2m = fmaf(hv.w, mW2[(k + 3) * H + t], a2m);
    }
    agg[(size_t)n * H + t] = a2m + (float)KNN * mb2[t];
  }
}

// ---------------- output ----------------

__global__ __launch_bounds__(64) void out_kernel(
    const float* __restrict__ nodes, const float* __restrict__ Wout,
    const float* __restrict__ bout, float* __restrict__ out)
{
  __shared__ float x[H];
  int n = blockIdx.x, t = threadIdx.x;
  x[t] = nodes[(size_t)n * H + t];
  x[64 + t] = nodes[(size_t)n * H + 64 + t];
  __syncthreads();
  if (t < AOUT) {
    float acc = bout[t];
    for (int hh = 0; hh < H; ++hh)
      acc = fmaf(x[hh], Wout[hh * AOUT + t], acc);
    out[n * AOUT + t] = acc;
  }
}

// ---------------- launch ----------------

extern "C" void kernel_launch(void* const* d_in, const int* in_sizes, int n_in,
                              void* d_out, int out_size, void* d_ws, size_t ws_size,
                              hipStream_t stream) {
  const float* nf    = (const float*)d_in[0];
  const float* ef    = (const float*)d_in[1];
  const int*   knn   = (const int*)  d_in[2];
  const float* Wn    = (const float*)d_in[3];
  const float* bn    = (const float*)d_in[4];
  const float* We    = (const float*)d_in[5];
  const float* be    = (const float*)d_in[6];
  const float* mW1   = (const float*)d_in[7];
  const float* mb1   = (const float*)d_in[8];
  const float* mW2   = (const float*)d_in[9];
  const float* mb2   = (const float*)d_in[10];
  const float* nW1   = (const float*)d_in[11];
  const float* nb1   = (const float*)d_in[12];
  const float* nW2   = (const float*)d_in[13];
  const float* nb2   = (const float*)d_in[14];
  const float* eW1   = (const float*)d_in[15];
  const float* eb1   = (const float*)d_in[16];
  const float* eW2   = (const float*)d_in[17];
  const float* eb2   = (const float*)d_in[18];
  const float* gn    = (const float*)d_in[19];
  const float* bnrm  = (const float*)d_in[20];
  const float* ge    = (const float*)d_in[21];
  const float* benrm = (const float*)d_in[22];
  const float* Wout  = (const float*)d_in[23];
  const float* bout  = (const float*)d_in[24];
  float* out = (float*)d_out;

  float* ws     = (float*)d_ws;
  float* nodes  = ws;                                  // N*H f32
  float* aggse  = ws + (size_t)NN * H;                 // N*H f32: agg, aliased by sp_e
  float* sp_m   = ws + (size_t)2 * NN * H;             // N*H f32
  u16* nodes_pk = (u16*)(ws + (size_t)3 * NN * H);     // N*256 u16
  u16* edges_pk = nodes_pk + (size_t)NN * 256;         // N*K*256 u16 (307 MB)
  u16* pk       = edges_pk + (size_t)NN * KNN * 256;   // packed-weight arena (~2 MB)
  u16* pkWe  = pk + PK_WE;
  u16* pkM1  = pk + PK_M1;
  u16* pkE1  = pk + PK_E1;
  u16* pkE2  = pk + PK_E2;
  u16* pkN1  = pk + PK_N1;
  u16* pkN2  = pk + PK_N2;
  u16* pkE1s = pk + PK_E1S;
  u16* pkM1s = pk + PK_M1S;
  float* sp_e = aggse;                  // alias: per-block read(agg) before write(sp_e)

  node_init_kernel<<<(NN * H + 255) / 256, 256, 0, stream>>>(nf, Wn, bn, nodes, nodes_pk);
  repack_many<<<239, 256, 0, stream>>>(We, mW1, eW1, eW2, nW1, nW2, pk);
  edge_init_mfma<<<NN * KNN / 32, 256, 0, stream>>>(ef, pkWe, be, edges_pk);

  // layer-0 message pass
  sp_kernel<<<NN / 2, 256, 0, stream>>>(nodes, mW1, mb1, sp_m);
  msg_agg_mfma<<<NN, 256, 0, stream>>>(nodes_pk, edges_pk, knn, sp_m,
      pkM1, mW2, mb2, aggse);

  for (int l = 0; l < NL; ++l) {
    int doSp = (l < 2) ? 1 : 0;
    node_upd_mfma<<<NN / 32, 256, 0, stream>>>(nodes, aggse, nodes_pk,
        pkN1 + l * 65536, nb1 + l * H, pkN2 + l * 32768, nb2 + l * H,
        gn + l * H, bnrm + l * H,
        doSp ? (pkE1s + l * 32768) : pkE1s, eb1 + l * H, sp_e,
        doSp ? (pkM1s + l * 32768) : pkM1s, mb1 + (doSp ? (l + 1) : 0) * H, sp_m,
        doSp);
    if (l < 2) {
      fused_edge_msg<<<NN, 256, 0, stream>>>(nodes_pk, edges_pk, knn,
          sp_e, sp_m,
          pkE1 + l * 65536, pkE2 + l * 32768, eb2 + l * H,
          ge + l * H, benrm + l * H,
          pkM1 + (l + 1) * 65536, mW2 + (size_t)(l + 1) * H * H,
          mb2 + (l + 1) * H, aggse, (l == 0) ? 1 : 0);
    }
  }
  out_kernel<<<NN, 64, 0, stream>>>(nodes, Wout, bout, out);
}

// Round 19
// 1553.920 us; speedup vs baseline: 1.6887x; 1.0052x over previous
//
#include <hip/hip_runtime.h>

// InverseFoldingModel: 3-layer message-passing GNN, MFMA bf16 hi/lo (2-term).
// R19 = R11 verbatim (last passing kernel, 1562us, absmax 0.015625).
// The K=128 neighbor-hoist branch (R12-R18) never cleared the threshold
// (0.069-0.21) and is abandoned; this re-banks the passing state.

#define NN   20000
#define KNN  30
#define H    128
#define EIN  240
#define NL   3
#define AOUT 20
#define CIN  384   // 2H + E
#define EPSV 1e-5f

typedef unsigned short u16;
typedef unsigned int   u32;
typedef float f32x16 __attribute__((ext_vector_type(16)));
typedef short s16x8  __attribute__((ext_vector_type(8)));
typedef short s16x4  __attribute__((ext_vector_type(4)));

#define MFMA32(acc, a, b) \
  asm("v_mfma_f32_32x32x16_bf16 %0, %1, %2, %0" : "+v"(acc) : "v"(a), "v"(b))

__device__ __forceinline__ u16 bh(float x) {           // f32 -> bf16 (RNE)
  u32 u = __float_as_uint(x);
  u += 0x7fffu + ((u >> 16) & 1u);
  return (u16)(u >> 16);
}
__device__ __forceinline__ float hf(u16 h) { return __uint_as_float(((u32)h) << 16); }
// packed 2x f32 -> 2x bf16 (lo16 = a, hi16 = b)
__device__ __forceinline__ u32 pk2(float a, float b) {
  u32 r; asm("v_cvt_pk_bf16_f32 %0, %1, %2" : "=v"(r) : "v"(a), "v"(b)); return r;
}

// packed-row layout: 128 elems -> 8 chunks x (16 hi u16 + 16 lo u16) = 256 u16
__device__ __forceinline__ int pko(int col) { return ((col >> 4) << 5) + (col & 15); }

// XOR-swizzled LDS index (u16 units); swizzle: byte ^= (row&7)<<4
__device__ __forceinline__ int axi(int row, int off) { return (row * 512 + off) ^ ((row & 7) << 3); }

// write 4 consecutive logical-k elements as hi4+lo4 (f32 source)
__device__ __forceinline__ void wrA4(u16* A, int row, int off, float4 v) {
  u16 h0 = bh(v.x), h1 = bh(v.y), h2 = bh(v.z), h3 = bh(v.w);
  s16x4 hv = { (short)h0, (short)h1, (short)h2, (short)h3 };
  s16x4 lv = { (short)bh(v.x - hf(h0)), (short)bh(v.y - hf(h1)),
               (short)bh(v.z - hf(h2)), (short)bh(v.w - hf(h3)) };
  *(s16x4*)(A + axi(row, off))      = hv;
  *(s16x4*)(A + axi(row, off + 16)) = lv;
}

// ---------------- weight repack (single launch) ----------------
// arena offsets (u16): pkWe 0 | pkM1 61440 | pkE1 258048 | pkE2 454656 |
// pkN1 552960 | pkN2 749568 | pkE1s 847872 | pkM1s 913408
#define PK_WE   0
#define PK_M1   61440
#define PK_E1   258048
#define PK_E2   454656
#define PK_N1   552960
#define PK_N2   749568
#define PK_E1S  847872
#define PK_M1S  913408

__global__ __launch_bounds__(256) void repack_many(
    const float* __restrict__ We, const float* __restrict__ mW1,
    const float* __restrict__ eW1, const float* __restrict__ eW2,
    const float* __restrict__ nW1, const float* __restrict__ nW2,
    u16* __restrict__ pk)
{
  int b = blockIdx.x;
  const float* W; u16* dst; int nS, s;
  if (b < 15)              { W = We; dst = pk + PK_WE; nS = 15; s = b; }
  else if ((b -= 15) < 48) { int l = b >> 4; s = b & 15; nS = 16;
                             W = mW1 + (size_t)l * CIN * H + 128 * H; dst = pk + PK_M1 + l * 65536; }
  else if ((b -= 48) < 48) { int l = b >> 4; s = b & 15; nS = 16;
                             W = eW1 + (size_t)l * CIN * H + 128 * H; dst = pk + PK_E1 + l * 65536; }
  else if ((b -= 48) < 24) { int l = b >> 3; s = b & 7; nS = 8;
                             W = eW2 + (size_t)l * H * H; dst = pk + PK_E2 + l * 32768; }
  else if ((b -= 24) < 48) { int l = b >> 4; s = b & 15; nS = 16;
                             W = nW1 + (size_t)l * 2 * H * H; dst = pk + PK_N1 + l * 65536; }
  else if ((b -= 48) < 24) { int l = b >> 3; s = b & 7; nS = 8;
                             W = nW2 + (size_t)l * H * H; dst = pk + PK_N2 + l * 32768; }
  else if ((b -= 24) < 16) { int l = b >> 3; s = b & 7; nS = 8;     // eW1 src rows, l=0,1
                             W = eW1 + (size_t)l * CIN * H; dst = pk + PK_E1S + l * 32768; }
  else { b -= 16;            int l = b >> 3; s = b & 7; nS = 8;     // mW1 src rows, layers 1,2
                             W = mW1 + (size_t)(l + 1) * CIN * H; dst = pk + PK_M1S + l * 32768; }
  int t = threadIdx.x;
  int c = t >> 6, ln = t & 63;
  int col = c * 32 + (ln & 31);
  int kb  = s * 16 + (ln >> 5) * 8;
  size_t base = ((size_t)(c * nS + s) * 2) * 512 + ln * 8;
  #pragma unroll
  for (int i = 0; i < 8; ++i) {
    float v = W[(size_t)(kb + i) * H + col];
    u16 hi = bh(v);
    dst[base + i]       = hi;
    dst[base + 512 + i] = bh(v - hf(hi));
  }
}

// ---------------- init ----------------

__global__ __launch_bounds__(256) void node_init_kernel(
    const float* __restrict__ nf, const float* __restrict__ Wn,
    const float* __restrict__ bn, float* __restrict__ nodes,
    u16* __restrict__ nodes_pk)
{
  int tid = blockIdx.x * 256 + threadIdx.x;
  if (tid >= NN * H) return;
  int n = tid >> 7, h = tid & (H - 1);
  float acc = bn[h];
  #pragma unroll
  for (int i = 0; i < 6; ++i)
    acc = fmaf(nf[n * 6 + i], Wn[i * H + h], acc);
  nodes[tid] = acc;
  u16 hi = bh(acc);
  nodes_pk[(size_t)n * 256 + pko(h)]      = hi;
  nodes_pk[(size_t)n * 256 + pko(h) + 16] = bh(acc - hf(hi));
}

// edges = ef @ We + be (K=240 -> 15 chunks), packed hi/lo output
__global__ __launch_bounds__(256) void edge_init_mfma(
    const float* __restrict__ ef, const u16* __restrict__ pkWe,
    const float* __restrict__ be, u16* __restrict__ edges_pk)
{
  __shared__ __align__(16) u16 A[32 * 512];
  int r0 = blockIdx.x * 32, t = threadIdx.x;
  for (int u = t; u < 1920; u += 256) {
    int r = u & 31, c = u >> 5;                   // c 0..59
    int k = c * 4;
    float4 v = *(const float4*)(ef + (size_t)(r0 + r) * EIN + k);
    wrA4(A, r, (k >> 4) * 32 + (k & 15), v);
  }
  __syncthreads();
  int w = t >> 6, l = t & 63;
  int lane31 = l & 31, half = l >> 5;
  float bev = be[w * 32 + lane31];
  f32x16 acc;
  #pragma unroll
  for (int r = 0; r < 16; ++r) acc[r] = bev;
  #pragma unroll
  for (int s = 0; s < 15; ++s) {
    s16x8 ah = *(const s16x8*)(A + axi(lane31, s * 32 + half * 8));
    s16x8 al = *(const s16x8*)(A + axi(lane31, s * 32 + 16 + half * 8));
    const u16* pb = pkWe + (size_t)((w * 15 + s) * 2) * 512 + l * 8;
    s16x8 bhv = *(const s16x8*)(pb);
    MFMA32(acc, ah, bhv);
    MFMA32(acc, al, bhv);
  }
  int col = w * 32 + lane31;
  #pragma unroll
  for (int r = 0; r < 16; ++r) {
    int row = (r & 3) + 8 * (r >> 2) + 4 * half;
    float v = acc[r];
    u16 hi = bh(v);
    size_t base = (size_t)(r0 + row) * 256 + pko(col);
    edges_pk[base]      = hi;
    edges_pk[base + 16] = bh(v - hf(hi));
  }
}

// ---------------- shared pieces ----------------

// copy-staging: A rows 0..29 = [nbr_pk row | edge_pk row]; rows 30,31 untouched.
__device__ __forceinline__ void stage_copy(
    const u16* __restrict__ nodes_pk, const u16* __restrict__ edges_pk,
    const int* __restrict__ knn, int n, int t, u16* A)
{
  int w = t >> 6, l = t & 63;
  int sub = l >> 5;
  int off = (l & 31) * 8;
  #pragma unroll
  for (int j = 0; j < 8; ++j) {
    int task = w * 16 + j * 2 + sub;
    int row  = task & 31;
    int part = task >> 5;           // 0 = nbr, 1 = edge
    if (row < KNN) {
      const u16* src = (part == 0)
        ? nodes_pk + (size_t)knn[n * KNN + row] * 256 + off
        : edges_pk + ((size_t)n * KNN + row) * 256 + off;
      s16x8 v = *(const s16x8*)src;
      *(s16x8*)(A + ((row * 512 + part * 256 + off) ^ ((row & 7) << 3))) = v;
    }
  }
}

// MLP1: acc = bias/sp (broadcast over rows) + A @ Wbc, K=256; 2-term (a_hi+a_lo)xW_hi
__device__ __forceinline__ f32x16 mlp1_mfma(
    const u16* A, const u16* __restrict__ pk, float spv, int l)
{
  int lane31 = l & 31, half = l >> 5;
  f32x16 acc;
  #pragma unroll
  for (int r = 0; r < 16; ++r) acc[r] = spv;
  #pragma unroll
  for (int s = 0; s < 16; ++s) {
    s16x8 ah = *(const s16x8*)(A + axi(lane31, s * 32 + half * 8));
    s16x8 al = *(const s16x8*)(A + axi(lane31, s * 32 + 16 + half * 8));
    const u16* pb = pk + (size_t)(s * 2) * 512 + l * 8;
    s16x8 bhv = *(const s16x8*)(pb);
    MFMA32(acc, ah, bhv);
    MFMA32(acc, al, bhv);
  }
  return acc;
}

// sp = nodes @ W[0:128] + b  (layer-0 message path only, initial nodes, f32)
__global__ __launch_bounds__(256) void sp_kernel(
    const float* __restrict__ nodes, const float* __restrict__ W,
    const float* __restrict__ b, float* __restrict__ sp)
{
  __shared__ __align__(16) float xl[2][H];
  int n0 = blockIdx.x * 2, t = threadIdx.x;
  int row = t >> 7, col = t & (H - 1);
  xl[row][col] = nodes[(size_t)(n0 + row) * H + col];
  __syncthreads();
  float acc = b[col];
  for (int k = 0; k < H; k += 4) {
    float4 xv = *(const float4*)(&xl[row][k]);
    acc = fmaf(xv.x, W[(k + 0) * H + col], acc);
    acc = fmaf(xv.y, W[(k + 1) * H + col], acc);
    acc = fmaf(xv.z, W[(k + 2) * H + col], acc);
    acc = fmaf(xv.w, W[(k + 3) * H + col], acc);
  }
  sp[(size_t)(n0 + row) * H + col] = acc;
}

// ---------------- per-layer kernels ----------------

__global__ __launch_bounds__(256) void msg_agg_mfma(
    const u16* __restrict__ nodes_pk, const u16* __restrict__ edges_pk,
    const int* __restrict__ knn, const float* __restrict__ sp,
    const u16* __restrict__ pkW1, const float* __restrict__ W2,
    const float* __restrict__ b2, float* __restrict__ agg)
{
  __shared__ __align__(16) u16 A[32 * 512];     // rows 30,31 = pad; hsum aliases row 30
  float* hsum = (float*)(A + 30 * 512);         // 128 f32
  int n = blockIdx.x, t = threadIdx.x;
  stage_copy(nodes_pk, edges_pk, knn, n, t, A);
  int w = t >> 6, l = t & 63;
  int lane31 = l & 31, half = l >> 5;
  float spv = sp[(size_t)n * H + w * 32 + lane31];
  __syncthreads();
  f32x16 acc = mlp1_mfma(A, pkW1 + (size_t)(w * 16) * 1024, spv, l);
  float ss = 0.f;
  #pragma unroll
  for (int r = 0; r < 16; ++r) {
    float v = fmaxf(acc[r], 0.f);
    if (r >= 14) v = half ? 0.f : v;           // mask pad rows 30,31
    ss += v;
  }
  ss += __shfl_xor(ss, 32);
  if (l < 32) hsum[w * 32 + l] = ss;
  __syncthreads();
  if (t < H) {
    float a2 = 0.f;
    for (int k = 0; k < H; k += 4) {
      float4 hv = *(const float4*)(hsum + k);
      a2 = fmaf(hv.x, W2[(k + 0) * H + t], a2);
      a2 = fmaf(hv.y, W2[(k + 1) * H + t], a2);
      a2 = fmaf(hv.z, W2[(k + 2) * H + t], a2);
      a2 = fmaf(hv.w, W2[(k + 3) * H + t], a2);
    }
    agg[(size_t)n * H + t] = a2 + (float)KNN * b2[t];
  }
}

// batched node update via MFMA: 32 nodes/block (625 blocks).
__global__ __launch_bounds__(256) void node_upd_mfma(
    float* __restrict__ nodes, const float* __restrict__ agg,
    u16* __restrict__ nodes_pk,
    const u16* __restrict__ pkW1, const float* __restrict__ b1,
    const u16* __restrict__ pkW2, const float* __restrict__ b2,
    const float* __restrict__ g, const float* __restrict__ bb,
    const u16* __restrict__ pkE1s, const float* __restrict__ eb1,
    float* __restrict__ sp_e,
    const u16* __restrict__ pkM1s, const float* __restrict__ mb1,
    float* __restrict__ sp_m, int doSp)
{
  __shared__ __align__(16) u16 A[32 * 512];     // 32 KB, all scratch aliased inside
  float* Af = (float*)A;
  float* mv = Af + 128;                         // row-0 agg half (dead P region)
  float* rs = Af + 160;
  int n0 = blockIdx.x * 32, t = threadIdx.x;
  int w = t >> 6, lane = t & 63;
  int lane31 = lane & 31, half = lane >> 5;
  int col = w * 32 + lane31;
  int coff = 256 + pko(col);
  // stage: tasks 0-31 copy nodes_pk rows; tasks 32-63 convert agg rows (f32->hi/lo)
  {
    int sub = lane >> 5;
    int off = (lane & 31) * 8;
    #pragma unroll
    for (int j = 0; j < 8; ++j) {
      int task = w * 16 + j * 2 + sub;
      int row = task & 31;
      if (task < 32) {
        s16x8 v = *(const s16x8*)(nodes_pk + (size_t)(n0 + row) * 256 + off);
        *(s16x8*)(A + ((row * 512 + off) ^ ((row & 7) << 3))) = v;
      } else {
        int k = (lane & 31) * 4;
        float4 v = *(const float4*)(agg + (size_t)(n0 + row) * H + k);
        wrA4(A, row, 256 + ((k >> 4) << 5) + (k & 15), v);
      }
    }
  }
  float b1v = b1[col];
  __syncthreads();                              // 1: A staged
  f32x16 acc;
  #pragma unroll
  for (int r = 0; r < 16; ++r) acc[r] = b1v;
  #pragma unroll
  for (int s = 0; s < 16; ++s) {
    s16x8 ah = *(const s16x8*)(A + axi(lane31, s * 32 + half * 8));
    s16x8 al = *(const s16x8*)(A + axi(lane31, s * 32 + 16 + half * 8));
    const u16* pb = pkW1 + (size_t)((w * 16 + s) * 2) * 512 + lane * 8;
    s16x8 bhv = *(const s16x8*)(pb);
    MFMA32(acc, ah, bhv);
    MFMA32(acc, al, bhv);
  }
  // residual = nodes hi+lo from A nodes half
  float res[16];
  #pragma unroll
  for (int r = 0; r < 16; ++r) {
    int row = (r & 3) + 8 * (r >> 2) + 4 * half;
    res[r] = hf(A[axi(row, pko(col))]) + hf(A[axi(row, pko(col) + 16)]);
  }
  __syncthreads();                              // 2: all A reads done
  // P = relu(acc) hi/lo into agg half
  #pragma unroll
  for (int r = 0; r < 16; r += 2) {
    int row0 = (r & 3) + 8 * (r >> 2) + 4 * half;
    float v0 = fmaxf(acc[r], 0.f), v1 = fmaxf(acc[r + 1], 0.f);
    u32 hp = pk2(v0, v1);
    float l0 = v0 - __uint_as_float(hp << 16);
    float l1 = v1 - __uint_as_float(hp & 0xffff0000u);
    u32 lp = pk2(l0, l1);
    A[axi(row0, coff)]          = (u16)hp;
    A[axi(row0, coff + 16)]     = (u16)lp;
    A[axi(row0 + 1, coff)]      = (u16)(hp >> 16);
    A[axi(row0 + 1, coff + 16)] = (u16)(lp >> 16);
  }
  __syncthreads();                              // 3: P ready
  float b2v = b2[col];
  f32x16 a2;
  #pragma unroll
  for (int r = 0; r < 16; ++r) a2[r] = b2v;
  #pragma unroll
  for (int s = 0; s < 8; ++s) {
    s16x8 ah = *(const s16x8*)(A + axi(lane31, 256 + s * 32 + half * 8));
    s16x8 al = *(const s16x8*)(A + axi(lane31, 256 + s * 32 + 16 + half * 8));
    const u16* pb = pkW2 + (size_t)((w * 8 + s) * 2) * 512 + lane * 8;
    s16x8 bhv = *(const s16x8*)(pb);
    MFMA32(a2, ah, bhv);
    MFMA32(a2, al, bhv);
  }
  float y[16];
  #pragma unroll
  for (int r = 0; r < 16; ++r) y[r] = a2[r] + res[r];
  __syncthreads();                              // 4: all P reads done
  // O = y f32 into nodes half, XOR swizzle
  #pragma unroll
  for (int r = 0; r < 16; ++r) {
    int row = (r & 3) + 8 * (r >> 2) + 4 * half;
    Af[row * 256 + (col ^ ((row & 7) << 2))] = y[r];
  }
  __syncthreads();                              // 5: O ready
  // stats: 8 threads per row x 32 rows = 256 threads
  {
    int srow = t >> 3, sub2 = t & 7;
    float s = 0.f, q = 0.f;
    #pragma unroll
    for (int qd = 0; qd < 4; ++qd) {
      int c0 = (sub2 * 16 + qd * 4) ^ ((srow & 7) << 2);
      float4 v = *(const float4*)(Af + srow * 256 + c0);
      s += v.x + v.y + v.z + v.w;
      q = fmaf(v.x, v.x, q); q = fmaf(v.y, v.y, q);
      q = fmaf(v.z, v.z, q); q = fmaf(v.w, v.w, q);
    }
    #pragma unroll
    for (int o2 = 1; o2 < 8; o2 <<= 1) {
      s += __shfl_xor(s, o2);
      q += __shfl_xor(q, o2);
    }
    if (sub2 == 0) {
      float mean = s * (1.f / (float)H);
      mv[srow] = mean;
      rs[srow] = rsqrtf(q * (1.f / (float)H) - mean * mean + EPSV);
    }
  }
  __syncthreads();                              // 6: stats ready
  float gv = g[col], bbv = bb[col];
  #pragma unroll
  for (int r = 0; r < 16; ++r) {
    int row = (r & 3) + 8 * (r >> 2) + 4 * half;
    y[r] = (y[r] - mv[row]) * rs[row] * gv + bbv;
  }
  __syncthreads();                              // 7: mv/rs reads done
  #pragma unroll
  for (int r = 0; r < 16; r += 2) {
    int row0 = (r & 3) + 8 * (r >> 2) + 4 * half;
    float o0 = y[r], o1 = y[r + 1];
    nodes[(size_t)(n0 + row0) * H + col]     = o0;
    nodes[(size_t)(n0 + row0 + 1) * H + col] = o1;
    u32 hp = pk2(o0, o1);
    float l0 = o0 - __uint_as_float(hp << 16);
    float l1 = o1 - __uint_as_float(hp & 0xffff0000u);
    u32 lp = pk2(l0, l1);
    size_t b0 = (size_t)(n0 + row0) * 256 + pko(col);
    nodes_pk[b0]            = (u16)hp;
    nodes_pk[b0 + 16]       = (u16)lp;
    nodes_pk[b0 + 256]      = (u16)(hp >> 16);
    nodes_pk[b0 + 256 + 16] = (u16)(lp >> 16);
    A[axi(row0, coff)]          = (u16)hp;
    A[axi(row0, coff + 16)]     = (u16)lp;
    A[axi(row0 + 1, coff)]      = (u16)(hp >> 16);
    A[axi(row0 + 1, coff + 16)] = (u16)(lp >> 16);
  }
  if (doSp) {
    __syncthreads();                            // 8: LN_out hi/lo in agg half
    float ebv = eb1[col];
    f32x16 aS, aQ;
    #pragma unroll
    for (int r = 0; r < 16; ++r) { aS[r] = 0.f; aQ[r] = 0.f; }
    #pragma unroll
    for (int s = 0; s < 8; ++s) {
      s16x8 ah = *(const s16x8*)(A + axi(lane31, 256 + s * 32 + half * 8));
      s16x8 al = *(const s16x8*)(A + axi(lane31, 256 + s * 32 + 16 + half * 8));
      s16x8 bE = *(const s16x8*)(pkE1s + (size_t)((w * 8 + s) * 2) * 512 + lane * 8);
      s16x8 bM = *(const s16x8*)(pkM1s + (size_t)((w * 8 + s) * 2) * 512 + lane * 8);
      MFMA32(aS, ah, bE);
      MFMA32(aS, al, bE);
      MFMA32(aQ, ah, bM);
      MFMA32(aQ, al, bM);
    }
    float mbv = mb1[col];
    #pragma unroll
    for (int r = 0; r < 16; ++r) {
      int row = (r & 3) + 8 * (r >> 2) + 4 * half;
      sp_e[(size_t)(n0 + row) * H + col] = aS[r] + ebv;
      sp_m[(size_t)(n0 + row) * H + col] = aQ[r] + mbv;
    }
  }
}

// fused: edge_upd(l) + msg_agg(l+1). All scratch inside A (32 KB).
__global__ __launch_bounds__(256) void fused_edge_msg(
    const u16* __restrict__ nodes_pk, u16* __restrict__ edges_pk,
    const int* __restrict__ knn,
    const float* __restrict__ sp_e, const float* __restrict__ sp_m,
    const u16* __restrict__ pkEW1, const u16* __restrict__ pkEW2,
    const float* __restrict__ eb2, const float* __restrict__ ge,
    const float* __restrict__ gbb,
    const u16* __restrict__ pkMW1, const float* __restrict__ mW2,
    const float* __restrict__ mb2, float* __restrict__ agg,
    int writeEdges)
{
  __shared__ __align__(16) u16 A[32 * 512];     // 32 KB total
  float* hsum = (float*)(A + 30 * 512);         // 128 f32 (pad row 30, nbr half)
  float* mv   = (float*)(A + 31 * 512);         // 32 f32 (pad row 31, nbr half)
  float* rs   = mv + 32;                        // 32 f32
  float* Af   = (float*)A;

  int n = blockIdx.x, t = threadIdx.x;
  stage_copy(nodes_pk, edges_pk, knn, n, t, A);
  int w = t >> 6, l = t & 63;
  int lane31 = l & 31, half = l >> 5;
  int col = w * 32 + lane31;
  float spe = sp_e[(size_t)n * H + col];
  float spm = sp_m[(size_t)n * H + col];
  int coff = 256 + pko(col);
  __syncthreads();                              // 1: A staged
  f32x16 acc = mlp1_mfma(A, pkEW1 + (size_t)(w * 16) * 1024, spe, l);
  float res[16];
  #pragma unroll
  for (int r = 0; r < 16; ++r) {
    int row = (r & 3) + 8 * (r >> 2) + 4 * half;
    res[r] = (row < KNN)
      ? hf(A[axi(row, coff)]) + hf(A[axi(row, coff + 16)]) : 0.f;
  }
  __syncthreads();                              // 2: all A-edge reads done
  #pragma unroll
  for (int r = 0; r < 16; r += 2) {
    int row0 = (r & 3) + 8 * (r >> 2) + 4 * half;
    if (row0 < KNN) {
      float v0 = fmaxf(acc[r], 0.f), v1 = fmaxf(acc[r + 1], 0.f);
      u32 hp = pk2(v0, v1);
      float l0 = v0 - __uint_as_float(hp << 16);
      float l1 = v1 - __uint_as_float(hp & 0xffff0000u);
      u32 lp = pk2(l0, l1);
      A[axi(row0, coff)]          = (u16)hp;
      A[axi(row0, coff + 16)]     = (u16)lp;
      A[axi(row0 + 1, coff)]      = (u16)(hp >> 16);
      A[axi(row0 + 1, coff + 16)] = (u16)(lp >> 16);
    }
  }
  __syncthreads();                              // 3: P ready
  float b2v = eb2[col];
  f32x16 a2;
  #pragma unroll
  for (int r = 0; r < 16; ++r) a2[r] = b2v;
  #pragma unroll
  for (int s = 0; s < 8; ++s) {
    s16x8 ah = *(const s16x8*)(A + axi(lane31, 256 + s * 32 + half * 8));
    s16x8 al = *(const s16x8*)(A + axi(lane31, 256 + s * 32 + 16 + half * 8));
    const u16* pb = pkEW2 + (size_t)((w * 8 + s) * 2) * 512 + l * 8;
    s16x8 bhv = *(const s16x8*)(pb);
    MFMA32(a2, ah, bhv);
    MFMA32(a2, al, bhv);
  }
  float y[16];
  #pragma unroll
  for (int r = 0; r < 16; ++r) y[r] = a2[r] + res[r];
  __syncthreads();                              // 4: all P reads done
  #pragma unroll
  for (int r = 0; r < 16; ++r) {
    int row = (r & 3) + 8 * (r >> 2) + 4 * half;
    if (row < KNN)
      Af[row * 256 + 128 + (col ^ ((row & 7) << 2))] = y[r];
  }
  __syncthreads();                              // 5: O ready
  {
    int srow = t >> 3, sub = t & 7;
    if (srow < KNN) {
      float s = 0.f, q = 0.f;
      #pragma unroll
      for (int qd = 0; qd < 4; ++qd) {
        int c0 = (sub * 16 + qd * 4) ^ ((srow & 7) << 2);
        float4 v = *(const float4*)(Af + srow * 256 + 128 + c0);
        s += v.x + v.y + v.z + v.w;
        q = fmaf(v.x, v.x, q); q = fmaf(v.y, v.y, q);
        q = fmaf(v.z, v.z, q); q = fmaf(v.w, v.w, q);
      }
      #pragma unroll
      for (int off = 1; off < 8; off <<= 1) {
        s += __shfl_xor(s, off);
        q += __shfl_xor(q, off);
      }
      if (sub == 0) {
        float mean = s * (1.f / (float)H);
        mv[srow] = mean;
        rs[srow] = rsqrtf(q * (1.f / (float)H) - mean * mean + EPSV);
      }
    }
  }
  __syncthreads();                              // 6: stats ready
  {
    float gv = ge[col], bbv = gbb[col];
    #pragma unroll
    for (int r = 0; r < 16; r += 2) {
      int row0 = (r & 3) + 8 * (r >> 2) + 4 * half;
      if (row0 < KNN) {
        float o0 = (y[r]     - mv[row0])     * rs[row0]     * gv + bbv;
        float o1 = (y[r + 1] - mv[row0 + 1]) * rs[row0 + 1] * gv + bbv;
        u32 hp = pk2(o0, o1);
        float l0 = o0 - __uint_as_float(hp << 16);
        float l1 = o1 - __uint_as_float(hp & 0xffff0000u);
        u32 lp = pk2(l0, l1);
        if (writeEdges) {
          size_t b0 = ((size_t)n * KNN + row0) * 256 + pko(col);
          edges_pk[b0]            = (u16)hp;
          edges_pk[b0 + 16]       = (u16)lp;
          edges_pk[b0 + 256]      = (u16)(hp >> 16);
          edges_pk[b0 + 256 + 16] = (u16)(lp >> 16);
        }
        A[axi(row0, coff)]          = (u16)hp;
        A[axi(row0, coff + 16)]     = (u16)lp;
        A[axi(row0 + 1, coff)]      = (u16)(hp >> 16);
        A[axi(row0 + 1, coff + 16)] = (u16)(lp >> 16);
      }
    }
  }
  __syncthreads();                              // 7: A = [nbr | new edges]
  f32x16 macc = mlp1_mfma(A, pkMW1 + (size_t)(w * 16) * 1024, spm, l);
  float ss = 0.f;
  #pragma unroll
  for (int r = 0; r < 16; ++r) {
    float v = fmaxf(macc[r], 0.f);
    if (r >= 14) v = half ? 0.f : v;
    ss += v;
  }
  ss += __shfl_xor(ss, 32);
  if (l < 32) hsum[w * 32 + l] = ss;
  __syncthreads();                              // 8: hsum ready
  if (t < H) {
    float a2m = 0.f;
    for (int k = 0; k < H; k += 4) {
      float4 hv = *(const float4*)(hsum + k);
      a2m = fmaf(hv.x, mW2[(k + 0) * H + t], a2m);
      a2m = fmaf(hv.y, mW2[(k + 1) * H + t], a2m);
      a2m = fmaf(hv.z, mW2[(k + 2) * H + t], a2m);
      a2m = fmaf(hv.w, mW2[(k + 3) * H + t], a2m);
    }
    agg[(size_t)n * H + t] = a2m + (float)KNN * mb2[t];
  }
}

// ---------------- output ----------------

__global__ __launch_bounds__(64) void out_kernel(
    const float* __restrict__ nodes, const float* __restrict__ Wout,
    const float* __restrict__ bout, float* __restrict__ out)
{
  __shared__ float x[H];
  int n = blockIdx.x, t = threadIdx.x;
  x[t] = nodes[(size_t)n * H + t];
  x[64 + t] = nodes[(size_t)n * H + 64 + t];
  __syncthreads();
  if (t < AOUT) {
    float acc = bout[t];
    for (int hh = 0; hh < H; ++hh)
      acc = fmaf(x[hh], Wout[hh * AOUT + t], acc);
    out[n * AOUT + t] = acc;
  }
}

// ---------------- launch ----------------

extern "C" void kernel_launch(void* const* d_in, const int* in_sizes, int n_in,
                              void* d_out, int out_size, void* d_ws, size_t ws_size,
                              hipStream_t stream) {
  const float* nf    = (const float*)d_in[0];
  const float* ef    = (const float*)d_in[1];
  const int*   knn   = (const int*)  d_in[2];
  const float* Wn    = (const float*)d_in[3];
  const float* bn    = (const float*)d_in[4];
  const float* We    = (const float*)d_in[5];
  const float* be    = (const float*)d_in[6];
  const float* mW1   = (const float*)d_in[7];
  const float* mb1   = (const float*)d_in[8];
  const float* mW2   = (const float*)d_in[9];
  const float* mb2   = (const float*)d_in[10];
  const float* nW1   = (const float*)d_in[11];
  const float* nb1   = (const float*)d_in[12];
  const float* nW2   = (const float*)d_in[13];
  const float* nb2   = (const float*)d_in[14];
  const float* eW1   = (const float*)d_in[15];
  const float* eb1   = (const float*)d_in[16];
  const float* eW2   = (const float*)d_in[17];
  const float* eb2   = (const float*)d_in[18];
  const float* gn    = (const float*)d_in[19];
  const float* bnrm  = (const float*)d_in[20];
  const float* ge    = (const float*)d_in[21];
  const float* benrm = (const float*)d_in[22];
  const float* Wout  = (const float*)d_in[23];
  const float* bout  = (const float*)d_in[24];
  float* out = (float*)d_out;

  float* ws     = (float*)d_ws;
  float* nodes  = ws;                                  // N*H f32
  float* aggse  = ws + (size_t)NN * H;                 // N*H f32: agg, aliased by sp_e
  float* sp_m   = ws + (size_t)2 * NN * H;             // N*H f32
  u16* nodes_pk = (u16*)(ws + (size_t)3 * NN * H);     // N*256 u16
  u16* edges_pk = nodes_pk + (size_t)NN * 256;         // N*K*256 u16 (307 MB)
  u16* pk       = edges_pk + (size_t)NN * KNN * 256;   // packed-weight arena (~2 MB)
  u16* pkWe  = pk + PK_WE;
  u16* pkM1  = pk + PK_M1;
  u16* pkE1  = pk + PK_E1;
  u16* pkE2  = pk + PK_E2;
  u16* pkN1  = pk + PK_N1;
  u16* pkN2  = pk + PK_N2;
  u16* pkE1s = pk + PK_E1S;
  u16* pkM1s = pk + PK_M1S;
  float* sp_e = aggse;                  // alias: per-block read(agg) before write(sp_e)

  node_init_kernel<<<(NN * H + 255) / 256, 256, 0, stream>>>(nf, Wn, bn, nodes, nodes_pk);
  repack_many<<<239, 256, 0, stream>>>(We, mW1, eW1, eW2, nW1, nW2, pk);
  edge_init_mfma<<<NN * KNN / 32, 256, 0, stream>>>(ef, pkWe, be, edges_pk);

  // layer-0 message pass
  sp_kernel<<<NN / 2, 256, 0, stream>>>(nodes, mW1, mb1, sp_m);
  msg_agg_mfma<<<NN, 256, 0, stream>>>(nodes_pk, edges_pk, knn, sp_m,
      pkM1, mW2, mb2, aggse);

  for (int l = 0; l < NL; ++l) {
    int doSp = (l < 2) ? 1 : 0;
    node_upd_mfma<<<NN / 32, 256, 0, stream>>>(nodes, aggse, nodes_pk,
        pkN1 + l * 65536, nb1 + l * H, pkN2 + l * 32768, nb2 + l * H,
        gn + l * H, bnrm + l * H,
        doSp ? (pkE1s + l * 32768) : pkE1s, eb1 + l * H, sp_e,
        doSp ? (pkM1s + l * 32768) : pkM1s, mb1 + (doSp ? (l + 1) : 0) * H, sp_m,
        doSp);
    if (l < 2) {
      fused_edge_msg<<<NN, 256, 0, stream>>>(nodes_pk, edges_pk, knn,
          sp_e, sp_m,
          pkE1 + l * 65536, pkE2 + l * 32768, eb2 + l * H,
          ge + l * H, benrm + l * H,
          pkM1 + (l + 1) * 65536, mW2 + (size_t)(l + 1) * H * H,
          mb2 + (l + 1) * H, aggse, (l == 0) ? 1 : 0);
    }
  }
  out_kernel<<<NN, 64, 0, stream>>>(nodes, Wout, bout, out);
}